// Round 3
// baseline (580.723 us; speedup 1.0000x reference)
//
#include <hip/hip_runtime.h>
#include <hip/hip_bf16.h>

typedef unsigned short u16;
typedef __attribute__((ext_vector_type(8))) __bf16 bf16x8;
typedef __attribute__((ext_vector_type(4))) float f32x4;

typedef __attribute__((address_space(1))) const void GVoid;
typedef __attribute__((address_space(3))) void LVoid;

__device__ __forceinline__ void async_load16(const u16* g, u16* l) {
    __builtin_amdgcn_global_load_lds((GVoid*)g, (LVoid*)l, 16, 0, 0);
}

__device__ __forceinline__ float bf2f(u16 u) {
    union { unsigned i; float f; } v; v.i = ((unsigned)u) << 16; return v.f;
}
__device__ __forceinline__ u16 f2bf(float f) {
    union { float f; unsigned i; } v; v.f = f;
    unsigned r = (v.i + 0x7FFFu + ((v.i >> 16) & 1u)) >> 16;
    return (u16)r;
}
// tanh-form GELU: gelu = x*(1 - 1/(1+e^{2t})), t=0.79788x+0.035677x^3
__device__ __forceinline__ float gelu_f(float x) {
    float t = x * fmaf(0.0356774081f, x * x, 0.7978845608f);
    float e = __expf(2.0f * t);
    float r = 1.0f / (e + 1.0f);
    return x - x * r;
}

// element offsets inside the canonical small-vector buffer (u16, bf16 values)
#define OP_E   0
#define PT_E   2304
#define POS_E  4864
#define CTX_B  6400
#define CTX_G  7424
#define CTX_BE 8448
#define S_B1   9472
#define S_G    9984
#define S_BE   10496
#define S_B2   11008
#define D_G    11012
#define D_BE   14084
#define D_B2   17156
#define A_B1   17216
#define A_B2   17728

// ---------------------------------------------------------------------------
struct SmallTab {
    const float* src[15];
    int off[15];
    int cnt[15];
};

__global__ __launch_bounds__(256) void convert_small(SmallTab tab, u16* __restrict__ dst)
{
    int idx = blockIdx.x * 256 + threadIdx.x;
#pragma unroll
    for (int e = 0; e < 15; ++e) {
        if (idx < tab.cnt[e]) {
            dst[tab.off[e] + idx] = f2bf(tab.src[e][idx]);
            return;
        }
        idx -= tab.cnt[e];
    }
}

// ---------------------------------------------------------------------------
// hidden f32 -> bf16, 16B/thread streaming.
// ---------------------------------------------------------------------------
__global__ __launch_bounds__(256) void convert_hidden(
    const float* __restrict__ src, u16* __restrict__ dst, int n8)
{
    int i = blockIdx.x * 256 + threadIdx.x;
    if (i >= n8) return;
    const float4* p = (const float4*)(src + (size_t)i * 8);
    float4 a = p[0], b = p[1];
    uint4 o;
    o.x = f2bf(a.x) | ((unsigned)f2bf(a.y) << 16);
    o.y = f2bf(a.z) | ((unsigned)f2bf(a.w) << 16);
    o.z = f2bf(b.x) | ((unsigned)f2bf(b.y) << 16);
    o.w = f2bf(b.z) | ((unsigned)f2bf(b.w) << 16);
    *(uint4*)(dst + (size_t)i * 8) = o;
}

// ---------------------------------------------------------------------------
// Transpose fp32 weights to B^T ([N,K] row-major) bf16.
// ---------------------------------------------------------------------------
__global__ __launch_bounds__(256) void transpose_all(
    const float* __restrict__ ctx_w, const float* __restrict__ sign_w1,
    const float* __restrict__ aux_w1, const float* __restrict__ dig_w1,
    u16* __restrict__ ctxWt, u16* __restrict__ BtAll)
{
    __shared__ u16 tl[32][33];
    int z = blockIdx.z;
    const float* src; u16* dst; size_t srcOff = 0; int srcLd, cols;
    if (z == 8) { src = ctx_w; dst = ctxWt; srcLd = 1024; cols = 1024; }
    else {
        srcLd = 512; cols = 512;
        if (z == 0) src = sign_w1;
        else if (z == 1) src = aux_w1;
        else { src = dig_w1; srcOff = (size_t)(z - 2) * 1280 * 512; }
        dst = BtAll + (size_t)z * 512 * 1024;
    }
    int n0 = blockIdx.x * 32;
    if (n0 >= cols) return;
    int k0 = blockIdx.y * 32;
    int t = threadIdx.x;
    int r = t >> 3;
    int c4 = (t & 7) * 4;
    float4 v = *(const float4*)&src[srcOff + (size_t)(k0 + r) * srcLd + n0 + c4];
    tl[r][c4 + 0] = f2bf(v.x); tl[r][c4 + 1] = f2bf(v.y);
    tl[r][c4 + 2] = f2bf(v.z); tl[r][c4 + 3] = f2bf(v.w);
    __syncthreads();
    ushort4 o;
    o.x = tl[c4 + 0][r]; o.y = tl[c4 + 1][r]; o.z = tl[c4 + 2][r]; o.w = tl[c4 + 3][r];
    *(ushort4*)&dst[(size_t)(n0 + r) * 1024 + k0 + c4] = o;
}

// ---------------------------------------------------------------------------
// Row-bias precompute (fp32 out)
// ---------------------------------------------------------------------------
__global__ __launch_bounds__(256) void precompute_bias(
    const float* __restrict__ ctx_w, const float* __restrict__ dig_w1,
    const float* __restrict__ op_embed, const float* __restrict__ pt_embed,
    const float* __restrict__ pos_embed, const float* __restrict__ dig_b1,
    const int* __restrict__ op_type,
    float* __restrict__ E_op, float* __restrict__ P_pt, float* __restrict__ dbias)
{
    int idx = blockIdx.x * 256 + threadIdx.x;
    if (idx < 8192) {
        int b = idx >> 10, n = idx & 1023;
        const float* e = op_embed + op_type[b] * 256;
        float s = 0.f;
        for (int q = 0; q < 256; ++q)
            s += e[q] * ctx_w[(size_t)(1024 + q) * 1024 + n];
        E_op[idx] = s;
    } else if (idx < 18432) {
        int i = idx - 8192;
        int v = i >> 10, n = i & 1023;
        const float* e = pt_embed + v * 256;
        float s = 0.f;
        for (int q = 0; q < 256; ++q)
            s += e[q] * ctx_w[(size_t)(1280 + q) * 1024 + n];
        P_pt[i] = s;
    } else if (idx < 21504) {
        int i = idx - 18432;
        int p = i >> 9, h = i & 511;
        const float* e = pos_embed + p * 256;
        float s = dig_b1[p * 512 + h];
        for (int q = 0; q < 256; ++q)
            s += e[q] * dig_w1[(size_t)p * 1280 * 512 + (size_t)(1024 + q) * 512 + h];
        dbias[i] = s;
    }
}

// ---------------------------------------------------------------------------
// Unified per-column vectors over the 4096 head_pre columns (fp32).
// ---------------------------------------------------------------------------
__global__ __launch_bounds__(256) void build_vec(
    const u16* __restrict__ csm, const float* __restrict__ dbias,
    float* __restrict__ biasAll, float* __restrict__ gammaAll,
    float* __restrict__ betaAll)
{
    int n = blockIdx.x * 256 + threadIdx.x;   // 0..4095
    float bi, g, be;
    if (n < 512) {
        bi = bf2f(csm[S_B1 + n]); g = bf2f(csm[S_G + n]); be = bf2f(csm[S_BE + n]);
    } else if (n < 1024) {
        bi = bf2f(csm[A_B1 + n - 512]); g = 1.f; be = 0.f;
    } else {
        int h = n - 1024;
        bi = dbias[h]; g = bf2f(csm[D_G + h]); be = bf2f(csm[D_BE + h]);
    }
    biasAll[n] = bi; gammaAll[n] = g; betaAll[n] = be;
}

// ---------------------------------------------------------------------------
// Build block-diagonal W2pad [128, 4096] bf16. Row = r*16+o.
// ---------------------------------------------------------------------------
__global__ __launch_bounds__(256) void build_w2pad(
    const float* __restrict__ sign_w2, const float* __restrict__ dig_w2,
    const float* __restrict__ aux_w2, u16* __restrict__ W2pad)
{
    int idx = blockIdx.x * 256 + threadIdx.x;   // 128*4096
    int row = idx >> 12, k = idx & 4095;
    int r = row >> 4, o = row & 15;
    float v = 0.f;
    if (r == 0) {
        if (o < 3 && k < 512) v = sign_w2[k * 3 + o];
    } else if (r == 7) {
        if (o == 0 && k >= 512 && k < 1024) v = aux_w2[k - 512];
    } else {
        int p = r - 1, lo = 1024 + p * 512;
        if (o < 10 && k >= lo && k < lo + 512) v = dig_w2[(size_t)p * 5120 + (k - lo) * 10 + o];
    }
    W2pad[idx] = f2bf(v);
}

// ---------------------------------------------------------------------------
// zero stats sums buffer
// ---------------------------------------------------------------------------
__global__ __launch_bounds__(256) void zero_stats(float2* __restrict__ stats, int n)
{
    int i = blockIdx.x * 256 + threadIdx.x;
    if (i < n) stats[i] = make_float2(0.f, 0.f);
}

// ---------------------------------------------------------------------------
// stats_fin: (sum, sumsq) over 512 -> (mean, rstd); aux slice identity.
// ---------------------------------------------------------------------------
__global__ __launch_bounds__(256) void stats_fin(float2* __restrict__ stats, int Rh)
{
    int i = blockIdx.x * 256 + threadIdx.x;
    if (i >= Rh * 8) return;
    int s = i & 7;
    float2 v = stats[i];
    float mean = v.x * (1.f / 512.f);
    float var = fmaxf(v.y * (1.f / 512.f) - mean * mean, 0.f);
    float2 o = make_float2(mean, rsqrtf(var + 1e-5f));
    if (s == 1) o = make_float2(0.f, 1.f);
    stats[i] = o;
}

// ---------------------------------------------------------------------------
// GEMM, 256x256-tile 8-phase schedule (m201 structure, plain HIP).
// C[M,N] = A[M,1024] @ Bt[N,1024]^T, bf16 in/out. M,N % 256 == 0, K = 1024.
//
// 8 waves (2Mx4N), 512 thr, BK=64, LDS 128 KiB = 2 dbuf x {A,B} x 2 half x
// [128 rows][8 granules of 16B], granule slot XOR-swizzled with (row&7) (T2).
// global_load_lds dest is linear; the global SOURCE is inverse-swizzled (the
// same involution), so swizzle is both-sides (rule #21).
// Per K-tile: 4 phases x {stage 1 half-tile, 16 MFMA}, one counted
// s_waitcnt vmcnt(6) per tile (T3/T4: 3 half-tiles always in flight),
// setprio around MFMA clusters (T5). Safety: all 24 frag ds_reads issue in
// phase 0 and are fenced by lgkmcnt(0)+barrier before any phase-1..3 stage
// can overwrite the current buffer.
//
// STATS=true (head GEMM): epilogue computes per-row (sum, sumsq) of
// (bf16-rounded acc + biasAll[col]) over this block's 256-col half-slice and
// atomicAdds into statSums[row*8 + slice] (zeroed beforehand; <=8 writers per
// address). bf16-rounding first makes the stats match what gemm_final will
// read back from C, i.e. identical semantics to the old ln_stats kernel.
// ---------------------------------------------------------------------------
template<bool STATS>
__global__ __launch_bounds__(512) void gemm_8ph(
    const u16* __restrict__ A, const u16* __restrict__ Bt, u16* __restrict__ C,
    int M, int N, const float* __restrict__ biasAll, float* __restrict__ statSums)
{
    __shared__ u16 smem[65536];   // 128 KiB
    const int tid = threadIdx.x;
    const int wid = tid >> 6, lane = tid & 63;
    const int quad = lane >> 4, r16 = lane & 15;
    const int wm = wid >> 2, wn = wid & 3;

    // T1: bijective XCD swizzle (nwg always divisible by 8 here)
    const int Mtiles = M >> 8;
    int flat = blockIdx.x + blockIdx.y * gridDim.x;
    int cpx = (Mtiles * (N >> 8)) >> 3;
    int swz = (flat & 7) * cpx + (flat >> 3);
    int bm = swz % Mtiles, bn = swz / Mtiles;
    const int m0 = bm << 8, n0 = bn << 8;

    // staging geometry: granule g = l*512 + tid; row = g>>3, slot = g&7
    // logical col granule = slot ^ (row&7)  (involution)
    const int rb = tid >> 3;                       // row within 64-row chunk
    const int cx = ((tid & 7) ^ (rb & 7)) * 8;     // inverse-swizzled col (elems)
    const u16* gA = A + (size_t)(m0 + rb) * 1024 + cx;
    const u16* gB = Bt + (size_t)(n0 + rb) * 1024 + cx;

#define STAGE(arr, h, tt) do { \
        u16* _d = smem + ((((tt) & 1) * 2 + (arr)) * 2 + (h)) * 8192 + wid * 512; \
        const u16* _s = ((arr) ? gB : gA) + (size_t)((h) * 128) * 1024 + (tt) * 64; \
        async_load16(_s, _d); \
        async_load16(_s + (size_t)64 * 1024, _d + 4096); \
    } while (0)

    // prologue: tile 0 fully (4 halves), tile 1 first 3 halves -> 14 loads;
    // vmcnt(6) completes exactly tile 0, leaves 3 half-tiles in flight.
    STAGE(0, 0, 0); STAGE(0, 1, 0); STAGE(1, 0, 0); STAGE(1, 1, 0);
    STAGE(0, 0, 1); STAGE(0, 1, 1); STAGE(1, 0, 1);
    asm volatile("s_waitcnt vmcnt(6)" ::: "memory");
    asm volatile("s_barrier" ::: "memory");

    f32x4 acc[8][4] = {};
    const int kx0 = ((quad) ^ (r16 & 7)) * 8;       // ks=0 swizzled slot (elems)
    const int kx1 = ((4 + quad) ^ (r16 & 7)) * 8;   // ks=1

#define QUAD(MF0, NF0) \
        _Pragma("unroll") \
        for (int ks = 0; ks < 2; ++ks) \
            _Pragma("unroll") \
            for (int mi = 0; mi < 4; ++mi) \
                _Pragma("unroll") \
                for (int nj = 0; nj < 2; ++nj) \
                    acc[(MF0) + mi][(NF0) + nj] = \
                        __builtin_amdgcn_mfma_f32_16x16x32_bf16( \
                            afr[(MF0) + mi][ks], bfr[(NF0) + nj][ks], \
                            acc[(MF0) + mi][(NF0) + nj], 0, 0, 0);

    for (int t = 0; t < 16; ++t) {
        const int cur = t & 1;
        const u16* sA = smem + cur * 32768 + wm * 8192 + r16 * 64;
        const u16* sB = smem + cur * 32768 + 16384 + (wn >> 1) * 8192
                        + ((wn & 1) * 64 + r16) * 64;

        // ---- phase 0: stage B-hi(t+1) [nxt buf]; read ALL frags; quad (0,0)
        if (t + 1 < 16) STAGE(1, 1, t + 1);
        bf16x8 afr[8][2], bfr[4][2];
#pragma unroll
        for (int mf = 0; mf < 8; ++mf) {
            afr[mf][0] = *(const bf16x8*)&sA[mf * 1024 + kx0];
            afr[mf][1] = *(const bf16x8*)&sA[mf * 1024 + kx1];
        }
#pragma unroll
        for (int nf = 0; nf < 4; ++nf) {
            bfr[nf][0] = *(const bf16x8*)&sB[nf * 1024 + kx0];
            bfr[nf][1] = *(const bf16x8*)&sB[nf * 1024 + kx1];
        }
        __builtin_amdgcn_s_setprio(1);
        QUAD(0, 0)
        __builtin_amdgcn_s_setprio(0);
        // fence: ALL reads of buf[cur] complete before any wave may issue a
        // stage that overwrites it (phases 1-3)
        asm volatile("s_waitcnt lgkmcnt(0)" ::: "memory");
        __builtin_amdgcn_sched_barrier(0);
        asm volatile("s_barrier" ::: "memory");
        __builtin_amdgcn_sched_barrier(0);

        // ---- phase 1: stage A-lo(t+2) [cur buf, now dead]; quad (0,1)
        if (t + 2 < 16) STAGE(0, 0, t + 2);
        __builtin_amdgcn_sched_barrier(0);
        __builtin_amdgcn_s_setprio(1);
        QUAD(0, 2)
        __builtin_amdgcn_s_setprio(0);
        __builtin_amdgcn_sched_barrier(0);
        asm volatile("s_barrier" ::: "memory");
        __builtin_amdgcn_sched_barrier(0);

        // ---- phase 2: stage A-hi(t+2); quad (1,0)
        if (t + 2 < 16) STAGE(0, 1, t + 2);
        __builtin_amdgcn_sched_barrier(0);
        __builtin_amdgcn_s_setprio(1);
        QUAD(4, 0)
        __builtin_amdgcn_s_setprio(0);
        __builtin_amdgcn_sched_barrier(0);
        asm volatile("s_barrier" ::: "memory");
        __builtin_amdgcn_sched_barrier(0);

        // ---- phase 3: stage B-lo(t+2); quad (1,1); counted vmcnt
        if (t + 2 < 16) STAGE(1, 0, t + 2);
        __builtin_amdgcn_sched_barrier(0);
        __builtin_amdgcn_s_setprio(1);
        QUAD(4, 2)
        __builtin_amdgcn_s_setprio(0);
        __builtin_amdgcn_sched_barrier(0);
        // steady state: 14 outstanding; oldest 8 = tile t+1's four halves
        if (t < 14)       asm volatile("s_waitcnt vmcnt(6)" ::: "memory");
        else if (t == 14) asm volatile("s_waitcnt vmcnt(0)" ::: "memory");
        asm volatile("s_barrier" ::: "memory");
    }
#undef QUAD
#undef STAGE

    if constexpr (STATS) {
        // per-lane columns: n0 + wn*64 + nf*16 + r16
        float bnf[4];
#pragma unroll
        for (int nf = 0; nf < 4; ++nf)
            bnf[nf] = biasAll[n0 + wn * 64 + nf * 16 + r16];
        const int sl = n0 >> 9;   // slice index 0..7
#pragma unroll
        for (int mf = 0; mf < 8; ++mf) {
#pragma unroll
            for (int r = 0; r < 4; ++r) {
                float sv = 0.f, s2v = 0.f;
#pragma unroll
                for (int nf = 0; nf < 4; ++nf) {
                    // bf16-round first: stats must describe the values
                    // gemm_final reads back from C.
                    float v = bf2f(f2bf(acc[mf][nf][r])) + bnf[nf];
                    sv += v; s2v += v * v;
                }
                sv += __shfl_xor(sv, 8);  s2v += __shfl_xor(s2v, 8);
                sv += __shfl_xor(sv, 4);  s2v += __shfl_xor(s2v, 4);
                sv += __shfl_xor(sv, 2);  s2v += __shfl_xor(s2v, 2);
                sv += __shfl_xor(sv, 1);  s2v += __shfl_xor(s2v, 1);
                if (r16 == 0) {
                    int row = m0 + wm * 128 + mf * 16 + quad * 4 + r;
                    atomicAdd(&statSums[((size_t)row * 8 + sl) * 2], sv);
                    atomicAdd(&statSums[((size_t)row * 8 + sl) * 2 + 1], s2v);
                }
            }
        }
    }

#pragma unroll
    for (int mf = 0; mf < 8; ++mf) {
#pragma unroll
        for (int nf = 0; nf < 4; ++nf) {
            size_t base = (size_t)(m0 + wm * 128 + mf * 16 + quad * 4) * N
                          + n0 + wn * 64 + nf * 16 + r16;
#pragma unroll
            for (int r = 0; r < 4; ++r)
                C[base + (size_t)r * N] = f2bf(acc[mf][nf][r]);
        }
    }
}

// ---------------------------------------------------------------------------
// ctx LN+GELU
// ---------------------------------------------------------------------------
__global__ __launch_bounds__(256) void ln_ctx_kernel(
    const u16* __restrict__ pre, const float* __restrict__ E_op,
    const float* __restrict__ P_pt, const int* __restrict__ ptype,
    const u16* __restrict__ csm, u16* __restrict__ ctx, int tokOff)
{
    __shared__ float red[8];
    int local = blockIdx.x;
    int token = tokOff + local;
    int b = token >> 11;            // T = 2048
    int pt = ptype[token];
    int tid = threadIdx.x;
    int c = tid * 4;
    int wid = tid >> 6, lane = tid & 63;

    ushort4 xp = *(const ushort4*)&pre[(size_t)local * 1024 + c];
    float4 eo = *(const float4*)&E_op[b * 1024 + c];
    float4 pp = *(const float4*)&P_pt[pt * 1024 + c];
    ushort4 cb4 = *(const ushort4*)&csm[CTX_B + c];
    float x[4];
    x[0] = bf2f(xp.x) + eo.x + pp.x + bf2f(cb4.x);
    x[1] = bf2f(xp.y) + eo.y + pp.y + bf2f(cb4.y);
    x[2] = bf2f(xp.z) + eo.z + pp.z + bf2f(cb4.z);
    x[3] = bf2f(xp.w) + eo.w + pp.w + bf2f(cb4.w);

    float s = x[0] + x[1] + x[2] + x[3];
    float s2 = x[0]*x[0] + x[1]*x[1] + x[2]*x[2] + x[3]*x[3];
    for (int off = 32; off; off >>= 1) { s += __shfl_xor(s, off); s2 += __shfl_xor(s2, off); }
    if (lane == 0) { red[wid] = s; red[4 + wid] = s2; }
    __syncthreads();
    s  = red[0] + red[1] + red[2] + red[3];
    s2 = red[4] + red[5] + red[6] + red[7];
    float mean = s * (1.f / 1024.f);
    float var = fmaxf(s2 * (1.f / 1024.f) - mean * mean, 0.f);
    float rs = rsqrtf(var + 1e-5f);

    ushort4 g4 = *(const ushort4*)&csm[CTX_G + c];
    ushort4 b4 = *(const ushort4*)&csm[CTX_BE + c];
    ushort4 o;
    o.x = f2bf(gelu_f((x[0] - mean) * rs * bf2f(g4.x) + bf2f(b4.x)));
    o.y = f2bf(gelu_f((x[1] - mean) * rs * bf2f(g4.y) + bf2f(b4.y)));
    o.z = f2bf(gelu_f((x[2] - mean) * rs * bf2f(g4.z) + bf2f(b4.z)));
    o.w = f2bf(gelu_f((x[3] - mean) * rs * bf2f(g4.w) + bf2f(b4.w)));
    *(ushort4*)&ctx[(size_t)token * 1024 + c] = o;
}

// ---------------------------------------------------------------------------
// gemm_final: out_pre[ks][Rh][128] = gelu(LN(A))@W2pad^T, K-split by 4.
// A-staging applies (x+bias-mean)*rs*gamma+beta then GELU on the fly.
// ---------------------------------------------------------------------------
__global__ __launch_bounds__(256) void gemm_final(
    const u16* __restrict__ A, const u16* __restrict__ W2pad,
    const float* __restrict__ biasAll, const float* __restrict__ gammaAll,
    const float* __restrict__ betaAll, const float2* __restrict__ stats,
    float* __restrict__ out_pre, int Rh)
{
    __shared__ u16 As[128 * 32];
    __shared__ u16 Bs[128 * 32];
    const int tid = threadIdx.x;
    const int wid = tid >> 6, lane = tid & 63;
    const int m0 = blockIdx.x * 128;
    const int ks = blockIdx.y, kbase = ks * 1024;
    const int mw = (wid >> 1) * 64, nw = (wid & 1) * 64;
    const int quad = lane >> 4, r16 = lane & 15;

    f32x4 acc[4][4] = {};

    const int srow = wid * 32 + (lane >> 2);
    const int scol = (lane & 3) * 8;
    const u16* gB = W2pad + (size_t)srow * 4096 + kbase + scol;
    u16* lB = Bs + wid * 32 * 32;

    const int r0 = tid >> 2;
    const int c8 = (tid & 3) * 8;

    for (int k0 = 0; k0 < 1024; k0 += 32) {
        async_load16(gB + k0, lB);
        async_load16(gB + k0 + (size_t)16 * 4096, lB + 16 * 32);
        int kk = kbase + k0 + c8;
        int sl = kk >> 9;
        float4 bi0 = *(const float4*)&biasAll[kk], bi1 = *(const float4*)&biasAll[kk + 4];
        float4 g0 = *(const float4*)&gammaAll[kk], g1 = *(const float4*)&gammaAll[kk + 4];
        float4 be0 = *(const float4*)&betaAll[kk], be1 = *(const float4*)&betaAll[kk + 4];
        float bb[8] = {bi0.x, bi0.y, bi0.z, bi0.w, bi1.x, bi1.y, bi1.z, bi1.w};
        float gg[8] = {g0.x, g0.y, g0.z, g0.w, g1.x, g1.y, g1.z, g1.w};
        float bt[8] = {be0.x, be0.y, be0.z, be0.w, be1.x, be1.y, be1.z, be1.w};
#pragma unroll
        for (int h = 0; h < 2; ++h) {
            int row = m0 + r0 + h * 64;
            const u16* ap = A + (size_t)row * 4096 + kk;
            ushort4 xa = ((const ushort4*)ap)[0];
            ushort4 xb = ((const ushort4*)ap)[1];
            u16 xr[8]; *(ushort4*)&xr[0] = xa; *(ushort4*)&xr[4] = xb;
            float2 st = stats[row * 8 + sl];
            u16 o[8];
#pragma unroll
            for (int j = 0; j < 8; ++j) {
                float v = (bf2f(xr[j]) + bb[j] - st.x) * st.y * gg[j] + bt[j];
                o[j] = f2bf(gelu_f(v));
            }
            *(uint4*)&As[(h * 64 + r0) * 32 + c8] = *(const uint4*)&o[0];
        }
        __syncthreads();

        bf16x8 af[4], bw[4];
#pragma unroll
        for (int i = 0; i < 4; ++i)
            af[i] = *(const bf16x8*)&As[(mw + i * 16 + r16) * 32 + quad * 8];
#pragma unroll
        for (int j = 0; j < 4; ++j)
            bw[j] = *(const bf16x8*)&Bs[(nw + j * 16 + r16) * 32 + quad * 8];
#pragma unroll
        for (int i = 0; i < 4; ++i)
#pragma unroll
            for (int j = 0; j < 4; ++j)
                acc[i][j] = __builtin_amdgcn_mfma_f32_16x16x32_bf16(
                    af[i], bw[j], acc[i][j], 0, 0, 0);
        __syncthreads();
    }

    float* op = out_pre + (size_t)ks * Rh * 128;
#pragma unroll
    for (int i = 0; i < 4; ++i) {
#pragma unroll
        for (int j = 0; j < 4; ++j) {
            int col = nw + j * 16 + r16;
            size_t base = (size_t)(m0 + mw + i * 16 + quad * 4) * 128 + col;
#pragma unroll
            for (int r = 0; r < 4; ++r)
                op[base + (size_t)r * 128] = acc[i][j][r];
        }
    }
}

// ---------------------------------------------------------------------------
// gather: sum 4 K-split planes of out_pre[ks][Rh][128] + out-bias -> outputs.
// ---------------------------------------------------------------------------
__global__ __launch_bounds__(256) void gather_out(
    const float* __restrict__ out_pre, const u16* __restrict__ csm,
    float* __restrict__ out, int tokOff, int Rh)
{
    int idx = blockIdx.x * 256 + threadIdx.x;
    if (idx >= Rh * 64) return;
    int local = idx >> 6;
    int c = idx & 63;
    int token = tokOff + local;
    size_t P = (size_t)Rh * 128;
    size_t base = (size_t)local * 128;
    int col;
    if (c < 3) col = c;
    else if (c == 63) col = 7 * 16;
    else { int d = c - 3; int p = d / 10; col = (p + 1) * 16 + (d - p * 10); }
    float v = out_pre[base + col] + out_pre[P + base + col]
            + out_pre[2 * P + base + col] + out_pre[3 * P + base + col];
    if (c < 3) {
        out[(size_t)token * 3 + c] = v + bf2f(csm[S_B2 + c]);
    } else if (c == 63) {
        out[1032192 + (size_t)token] = v + bf2f(csm[A_B2]);
    } else {
        int d = c - 3;
        int p = d / 10, o = d - p * 10;
        out[49152 + ((size_t)token * 6 + p) * 10 + o] = v + bf2f(csm[D_B2 + p * 10 + o]);
    }
}

// ---------------------------------------------------------------------------
extern "C" void kernel_launch(void* const* d_in, const int* in_sizes, int n_in,
                              void* d_out, int out_size, void* d_ws, size_t ws_size,
                              hipStream_t stream) {
    const float* hidden    = (const float*)d_in[0];
    const int*   op_type   = (const int*)d_in[1];
    const int*   pt_type   = (const int*)d_in[2];
    const float* op_embed  = (const float*)d_in[3];
    const float* pt_embed  = (const float*)d_in[4];
    const float* pos_embed = (const float*)d_in[5];
    const float* ctx_w     = (const float*)d_in[6];
    const float* sign_w1   = (const float*)d_in[10];
    const float* sign_w2   = (const float*)d_in[14];
    const float* dig_w1    = (const float*)d_in[16];
    const float* dig_b1    = (const float*)d_in[17];
    const float* dig_w2    = (const float*)d_in[20];
    const float* aux_w1    = (const float*)d_in[22];
    const float* aux_w2    = (const float*)d_in[24];

    char* ws = (char*)d_ws;
    u16*    ctxWt    = (u16*)(ws + 0);           //  2,097,152 (later W2pad overlay)
    u16*    BtAll    = (u16*)(ws + 2097152);     //  8,388,608
    float*  E_op     = (float*)(ws + 10485760);  //     32,768
    float*  P_pt     = (float*)(ws + 10518528);  //     40,960
    float*  dbias    = (float*)(ws + 10559488);  //     12,288
    u16*    csm      = (u16*)(ws + 10571776);    //     65,536
    float*  biasAll  = (float*)(ws + 10637312);  //     16,384
    float*  gammaAll = (float*)(ws + 10653696);  //     16,384
    float*  betaAll  = (float*)(ws + 10670080);  //     16,384
    float2* stats    = (float2*)(ws + 10686464); //  1,048,576 (max Rh*8*8)
    u16*    context  = (u16*)(ws + 11735040);    // 33,554,432
    u16*    scratch  = (u16*)(ws + 45289472);    // remainder (head_pre / ctx_pre)
    u16*    W2pad    = ctxWt;
    size_t S = (ws_size > 45289472) ? ws_size - 45289472 : 0;

    int Rc = 16384;
    while ((size_t)Rc * 2048 > S && Rc > 512) Rc >>= 1;
    int Rh = 16384;
    while ((size_t)Rh * 8192 > S && Rh > 256) Rh >>= 1;   // 256-row tiles

    float* out = (float*)d_out;

    SmallTab tab;
    const float* srcs[15] = { op_embed, pt_embed, pos_embed,
                              (const float*)d_in[7], (const float*)d_in[8], (const float*)d_in[9],
                              (const float*)d_in[11], (const float*)d_in[12], (const float*)d_in[13],
                              (const float*)d_in[15],
                              (const float*)d_in[18], (const float*)d_in[19], (const float*)d_in[21],
                              (const float*)d_in[23], (const float*)d_in[25] };
    const int offs[15] = { OP_E, PT_E, POS_E, CTX_B, CTX_G, CTX_BE,
                           S_B1, S_G, S_BE, S_B2,
                           D_G, D_BE, D_B2, A_B1, A_B2 };
    const int cnts[15] = { 2304, 2560, 1536, 1024, 1024, 1024,
                           512, 512, 512, 3,
                           3072, 3072, 60, 512, 1 };
    for (int i = 0; i < 15; ++i) { tab.src[i] = srcs[i]; tab.off[i] = offs[i]; tab.cnt[i] = cnts[i]; }
    convert_small<<<70, 256, 0, stream>>>(tab, csm);

    transpose_all<<<dim3(32, 32, 9), 256, 0, stream>>>(
        ctx_w, sign_w1, aux_w1, dig_w1, ctxWt, BtAll);
    precompute_bias<<<84, 256, 0, stream>>>(
        ctx_w, dig_w1, op_embed, pt_embed, pos_embed, dig_b1, op_type,
        E_op, P_pt, dbias);
    build_vec<<<16, 256, 0, stream>>>(csm, dbias, biasAll, gammaAll, betaAll);

    // hidden f32 -> bf16, overlaid on the context buffer (rows die chunk-wise
    // exactly when ln_ctx overwrites them, after this chunk's gemm consumed them)
    u16* hbf16 = context;
    convert_hidden<<<8192, 256, 0, stream>>>(hidden, hbf16, 16384 * 1024 / 8);

    // context = gelu(LN(hidden @ ctx_w[:1024] + E_op + P_pt + b))
    for (int t0 = 0; t0 < 16384; t0 += Rc) {
        gemm_8ph<false><<<dim3(Rc / 256, 4), 512, 0, stream>>>(
            hbf16 + (size_t)t0 * 1024, ctxWt, scratch, Rc, 1024, nullptr, nullptr);
        ln_ctx_kernel<<<Rc, 256, 0, stream>>>(
            scratch, E_op, P_pt, pt_type, csm, context, t0);
    }

    // W2pad overlays ctxWt (now dead)
    build_w2pad<<<2048, 256, 0, stream>>>(sign_w2, dig_w2, aux_w2, W2pad);

    // head pipeline per chunk: 8-phase GEMM (+fused LN stats) -> stats_fin ->
    // fused LN+GELU GEMM -> gather
    for (int t0 = 0; t0 < 16384; t0 += Rh) {
        zero_stats<<<(Rh * 8 + 255) / 256, 256, 0, stream>>>(stats, Rh * 8);
        gemm_8ph<true><<<dim3(Rh / 256, 16), 512, 0, stream>>>(
            context + (size_t)t0 * 1024, BtAll, scratch, Rh, 4096,
            biasAll, (float*)stats);
        stats_fin<<<(Rh * 8 + 255) / 256, 256, 0, stream>>>(stats, Rh);
        // out_pre overlays this chunk's (now dead) context rows: 4*Rh*128*4 B == Rh*2048 B
        float* out_pre = (float*)(context + (size_t)t0 * 1024);
        gemm_final<<<dim3(Rh / 128, 4), 256, 0, stream>>>(
            scratch, W2pad, biasAll, gammaAll, betaAll, stats, out_pre, Rh);
        gather_out<<<(Rh * 64 + 255) / 256, 256, 0, stream>>>(
            out_pre, csm, out, t0, Rh);
    }
}

// Round 4
// 526.042 us; speedup vs baseline: 1.1039x; 1.1039x over previous
//
#include <hip/hip_runtime.h>
#include <hip/hip_bf16.h>

typedef unsigned short u16;
typedef __attribute__((ext_vector_type(8))) __bf16 bf16x8;
typedef __attribute__((ext_vector_type(4))) float f32x4;

typedef __attribute__((address_space(1))) const void GVoid;
typedef __attribute__((address_space(3))) void LVoid;

__device__ __forceinline__ void async_load16(const u16* g, u16* l) {
    __builtin_amdgcn_global_load_lds((GVoid*)g, (LVoid*)l, 16, 0, 0);
}

__device__ __forceinline__ float bf2f(u16 u) {
    union { unsigned i; float f; } v; v.i = ((unsigned)u) << 16; return v.f;
}
__device__ __forceinline__ u16 f2bf(float f) {
    union { float f; unsigned i; } v; v.f = f;
    unsigned r = (v.i + 0x7FFFu + ((v.i >> 16) & 1u)) >> 16;
    return (u16)r;
}
// tanh-form GELU: gelu = x*(1 - 1/(1+e^{2t})), t=0.79788x+0.035677x^3
__device__ __forceinline__ float gelu_f(float x) {
    float t = x * fmaf(0.0356774081f, x * x, 0.7978845608f);
    float e = __expf(2.0f * t);
    float r = 1.0f / (e + 1.0f);
    return x - x * r;
}

// element offsets inside the canonical small-vector buffer (u16, bf16 values)
#define OP_E   0
#define PT_E   2304
#define POS_E  4864
#define CTX_B  6400
#define CTX_G  7424
#define CTX_BE 8448
#define S_B1   9472
#define S_G    9984
#define S_BE   10496
#define S_B2   11008
#define D_G    11012
#define D_BE   14084
#define D_B2   17156
#define A_B1   17216
#define A_B2   17728

// ---------------------------------------------------------------------------
struct SmallTab {
    const float* src[15];
    int off[15];
    int cnt[15];
};

__global__ __launch_bounds__(256) void convert_small(SmallTab tab, u16* __restrict__ dst)
{
    int idx = blockIdx.x * 256 + threadIdx.x;
#pragma unroll
    for (int e = 0; e < 15; ++e) {
        if (idx < tab.cnt[e]) {
            dst[tab.off[e] + idx] = f2bf(tab.src[e][idx]);
            return;
        }
        idx -= tab.cnt[e];
    }
}

// ---------------------------------------------------------------------------
// hidden f32 -> bf16, 16B/thread streaming.
// ---------------------------------------------------------------------------
__global__ __launch_bounds__(256) void convert_hidden(
    const float* __restrict__ src, u16* __restrict__ dst, int n8)
{
    int i = blockIdx.x * 256 + threadIdx.x;
    if (i >= n8) return;
    const float4* p = (const float4*)(src + (size_t)i * 8);
    float4 a = p[0], b = p[1];
    uint4 o;
    o.x = f2bf(a.x) | ((unsigned)f2bf(a.y) << 16);
    o.y = f2bf(a.z) | ((unsigned)f2bf(a.w) << 16);
    o.z = f2bf(b.x) | ((unsigned)f2bf(b.y) << 16);
    o.w = f2bf(b.z) | ((unsigned)f2bf(b.w) << 16);
    *(uint4*)(dst + (size_t)i * 8) = o;
}

// ---------------------------------------------------------------------------
// Transpose fp32 weights to B^T ([N,K] row-major) bf16.
// ---------------------------------------------------------------------------
__global__ __launch_bounds__(256) void transpose_all(
    const float* __restrict__ ctx_w, const float* __restrict__ sign_w1,
    const float* __restrict__ aux_w1, const float* __restrict__ dig_w1,
    u16* __restrict__ ctxWt, u16* __restrict__ BtAll)
{
    __shared__ u16 tl[32][33];
    int z = blockIdx.z;
    const float* src; u16* dst; size_t srcOff = 0; int srcLd, cols;
    if (z == 8) { src = ctx_w; dst = ctxWt; srcLd = 1024; cols = 1024; }
    else {
        srcLd = 512; cols = 512;
        if (z == 0) src = sign_w1;
        else if (z == 1) src = aux_w1;
        else { src = dig_w1; srcOff = (size_t)(z - 2) * 1280 * 512; }
        dst = BtAll + (size_t)z * 512 * 1024;
    }
    int n0 = blockIdx.x * 32;
    if (n0 >= cols) return;
    int k0 = blockIdx.y * 32;
    int t = threadIdx.x;
    int r = t >> 3;
    int c4 = (t & 7) * 4;
    float4 v = *(const float4*)&src[srcOff + (size_t)(k0 + r) * srcLd + n0 + c4];
    tl[r][c4 + 0] = f2bf(v.x); tl[r][c4 + 1] = f2bf(v.y);
    tl[r][c4 + 2] = f2bf(v.z); tl[r][c4 + 3] = f2bf(v.w);
    __syncthreads();
    ushort4 o;
    o.x = tl[c4 + 0][r]; o.y = tl[c4 + 1][r]; o.z = tl[c4 + 2][r]; o.w = tl[c4 + 3][r];
    *(ushort4*)&dst[(size_t)(n0 + r) * 1024 + k0 + c4] = o;
}

// ---------------------------------------------------------------------------
// Row-bias precompute (fp32 out)
// ---------------------------------------------------------------------------
__global__ __launch_bounds__(256) void precompute_bias(
    const float* __restrict__ ctx_w, const float* __restrict__ dig_w1,
    const float* __restrict__ op_embed, const float* __restrict__ pt_embed,
    const float* __restrict__ pos_embed, const float* __restrict__ dig_b1,
    const int* __restrict__ op_type,
    float* __restrict__ E_op, float* __restrict__ P_pt, float* __restrict__ dbias)
{
    int idx = blockIdx.x * 256 + threadIdx.x;
    if (idx < 8192) {
        int b = idx >> 10, n = idx & 1023;
        const float* e = op_embed + op_type[b] * 256;
        float s = 0.f;
        for (int q = 0; q < 256; ++q)
            s += e[q] * ctx_w[(size_t)(1024 + q) * 1024 + n];
        E_op[idx] = s;
    } else if (idx < 18432) {
        int i = idx - 8192;
        int v = i >> 10, n = i & 1023;
        const float* e = pt_embed + v * 256;
        float s = 0.f;
        for (int q = 0; q < 256; ++q)
            s += e[q] * ctx_w[(size_t)(1280 + q) * 1024 + n];
        P_pt[i] = s;
    } else if (idx < 21504) {
        int i = idx - 18432;
        int p = i >> 9, h = i & 511;
        const float* e = pos_embed + p * 256;
        float s = dig_b1[p * 512 + h];
        for (int q = 0; q < 256; ++q)
            s += e[q] * dig_w1[(size_t)p * 1280 * 512 + (size_t)(1024 + q) * 512 + h];
        dbias[i] = s;
    }
}

// ---------------------------------------------------------------------------
// Unified per-column vectors over the 4096 head_pre columns (fp32).
// ---------------------------------------------------------------------------
__global__ __launch_bounds__(256) void build_vec(
    const u16* __restrict__ csm, const float* __restrict__ dbias,
    float* __restrict__ biasAll, float* __restrict__ gammaAll,
    float* __restrict__ betaAll)
{
    int n = blockIdx.x * 256 + threadIdx.x;   // 0..4095
    float bi, g, be;
    if (n < 512) {
        bi = bf2f(csm[S_B1 + n]); g = bf2f(csm[S_G + n]); be = bf2f(csm[S_BE + n]);
    } else if (n < 1024) {
        bi = bf2f(csm[A_B1 + n - 512]); g = 1.f; be = 0.f;
    } else {
        int h = n - 1024;
        bi = dbias[h]; g = bf2f(csm[D_G + h]); be = bf2f(csm[D_BE + h]);
    }
    biasAll[n] = bi; gammaAll[n] = g; betaAll[n] = be;
}

// ---------------------------------------------------------------------------
// Build block-diagonal W2pad [128, 4096] bf16. Row = r*16+o.
// ---------------------------------------------------------------------------
__global__ __launch_bounds__(256) void build_w2pad(
    const float* __restrict__ sign_w2, const float* __restrict__ dig_w2,
    const float* __restrict__ aux_w2, u16* __restrict__ W2pad)
{
    int idx = blockIdx.x * 256 + threadIdx.x;   // 128*4096
    int row = idx >> 12, k = idx & 4095;
    int r = row >> 4, o = row & 15;
    float v = 0.f;
    if (r == 0) {
        if (o < 3 && k < 512) v = sign_w2[k * 3 + o];
    } else if (r == 7) {
        if (o == 0 && k >= 512 && k < 1024) v = aux_w2[k - 512];
    } else {
        int p = r - 1, lo = 1024 + p * 512;
        if (o < 10 && k >= lo && k < lo + 512) v = dig_w2[(size_t)p * 5120 + (k - lo) * 10 + o];
    }
    W2pad[idx] = f2bf(v);
}

// ---------------------------------------------------------------------------
// stats_fin: combine the two 256-col partials per (row, 512-slice) ->
// (mean, rstd); aux slice (s==1) identity. partials layout: [16][Rh] float2.
// ---------------------------------------------------------------------------
__global__ __launch_bounds__(256) void stats_fin(
    const float2* __restrict__ partials, float2* __restrict__ stats, int Rh)
{
    int i = blockIdx.x * 256 + threadIdx.x;
    if (i >= Rh * 8) return;
    int row = i >> 3, s = i & 7;
    float2 o;
    if (s == 1) {
        o = make_float2(0.f, 1.f);
    } else {
        float2 a = partials[(size_t)(2 * s) * Rh + row];
        float2 b = partials[(size_t)(2 * s + 1) * Rh + row];
        float sm = a.x + b.x, s2 = a.y + b.y;
        float mean = sm * (1.f / 512.f);
        float var = fmaxf(s2 * (1.f / 512.f) - mean * mean, 0.f);
        o = make_float2(mean, rsqrtf(var + 1e-5f));
    }
    stats[i] = o;
}

// ---------------------------------------------------------------------------
// GEMM, 256x256-tile 8-phase schedule (m201 structure, plain HIP).
// C[M,N] = A[M,1024] @ Bt[N,1024]^T, bf16 in/out. M,N % 256 == 0, K = 1024.
//
// 8 waves (2Mx4N), 512 thr, BK=64, LDS 128 KiB = 2 dbuf x {A,B} x 2 half x
// [128 rows][8 granules of 16B], granule slot XOR-swizzled with (row&7) (T2).
// global_load_lds dest is linear; the global SOURCE is inverse-swizzled (the
// same involution), so swizzle is both-sides (rule #21).
// Per K-tile: 4 phases x {stage 1 half-tile, 16 MFMA}, one counted
// s_waitcnt vmcnt(6) per tile (T3/T4: 3 half-tiles always in flight),
// setprio around MFMA clusters (T5). Safety: all 24 frag ds_reads issue in
// phase 0 and are fenced by lgkmcnt(0)+barrier before any phase-1..3 stage
// can overwrite the current buffer.
//
// STATS=true (head GEMM): epilogue computes per-row (sum, sumsq) of
// (bf16-rounded acc + biasAll[col]) over this block's 256 cols via shfl +
// LDS combine (smem is dead after the K-loop), then ONE plain coalesced
// float2 store per row into partials[bn][m0+row]. NO ATOMICS (round-3
// lesson: device-scope atomics = memory-side RMW, +115 us).
// ---------------------------------------------------------------------------
template<bool STATS>
__global__ __launch_bounds__(512) void gemm_8ph(
    const u16* __restrict__ A, const u16* __restrict__ Bt, u16* __restrict__ C,
    int M, int N, const float* __restrict__ biasAll, float2* __restrict__ partials)
{
    __shared__ u16 smem[65536];   // 128 KiB
    const int tid = threadIdx.x;
    const int wid = tid >> 6, lane = tid & 63;
    const int quad = lane >> 4, r16 = lane & 15;
    const int wm = wid >> 2, wn = wid & 3;

    // T1: bijective XCD swizzle (nwg always divisible by 8 here)
    const int Mtiles = M >> 8;
    int flat = blockIdx.x + blockIdx.y * gridDim.x;
    int cpx = (Mtiles * (N >> 8)) >> 3;
    int swz = (flat & 7) * cpx + (flat >> 3);
    int bm = swz % Mtiles, bn = swz / Mtiles;
    const int m0 = bm << 8, n0 = bn << 8;

    // staging geometry: granule g = l*512 + tid; row = g>>3, slot = g&7
    // logical col granule = slot ^ (row&7)  (involution)
    const int rb = tid >> 3;                       // row within 64-row chunk
    const int cx = ((tid & 7) ^ (rb & 7)) * 8;     // inverse-swizzled col (elems)
    const u16* gA = A + (size_t)(m0 + rb) * 1024 + cx;
    const u16* gB = Bt + (size_t)(n0 + rb) * 1024 + cx;

#define STAGE(arr, h, tt) do { \
        u16* _d = smem + ((((tt) & 1) * 2 + (arr)) * 2 + (h)) * 8192 + wid * 512; \
        const u16* _s = ((arr) ? gB : gA) + (size_t)((h) * 128) * 1024 + (tt) * 64; \
        async_load16(_s, _d); \
        async_load16(_s + (size_t)64 * 1024, _d + 4096); \
    } while (0)

    // prologue: tile 0 fully (4 halves), tile 1 first 3 halves -> 14 loads;
    // vmcnt(6) completes exactly tile 0, leaves 3 half-tiles in flight.
    STAGE(0, 0, 0); STAGE(0, 1, 0); STAGE(1, 0, 0); STAGE(1, 1, 0);
    STAGE(0, 0, 1); STAGE(0, 1, 1); STAGE(1, 0, 1);
    asm volatile("s_waitcnt vmcnt(6)" ::: "memory");
    asm volatile("s_barrier" ::: "memory");

    f32x4 acc[8][4] = {};
    const int kx0 = ((quad) ^ (r16 & 7)) * 8;       // ks=0 swizzled slot (elems)
    const int kx1 = ((4 + quad) ^ (r16 & 7)) * 8;   // ks=1

#define QUAD(MF0, NF0) \
        _Pragma("unroll") \
        for (int ks = 0; ks < 2; ++ks) \
            _Pragma("unroll") \
            for (int mi = 0; mi < 4; ++mi) \
                _Pragma("unroll") \
                for (int nj = 0; nj < 2; ++nj) \
                    acc[(MF0) + mi][(NF0) + nj] = \
                        __builtin_amdgcn_mfma_f32_16x16x32_bf16( \
                            afr[(MF0) + mi][ks], bfr[(NF0) + nj][ks], \
                            acc[(MF0) + mi][(NF0) + nj], 0, 0, 0);

    for (int t = 0; t < 16; ++t) {
        const int cur = t & 1;
        const u16* sA = smem + cur * 32768 + wm * 8192 + r16 * 64;
        const u16* sB = smem + cur * 32768 + 16384 + (wn >> 1) * 8192
                        + ((wn & 1) * 64 + r16) * 64;

        // ---- phase 0: stage B-hi(t+1) [nxt buf]; read ALL frags; quad (0,0)
        if (t + 1 < 16) STAGE(1, 1, t + 1);
        bf16x8 afr[8][2], bfr[4][2];
#pragma unroll
        for (int mf = 0; mf < 8; ++mf) {
            afr[mf][0] = *(const bf16x8*)&sA[mf * 1024 + kx0];
            afr[mf][1] = *(const bf16x8*)&sA[mf * 1024 + kx1];
        }
#pragma unroll
        for (int nf = 0; nf < 4; ++nf) {
            bfr[nf][0] = *(const bf16x8*)&sB[nf * 1024 + kx0];
            bfr[nf][1] = *(const bf16x8*)&sB[nf * 1024 + kx1];
        }
        __builtin_amdgcn_s_setprio(1);
        QUAD(0, 0)
        __builtin_amdgcn_s_setprio(0);
        // fence: ALL reads of buf[cur] complete before any wave may issue a
        // stage that overwrites it (phases 1-3)
        asm volatile("s_waitcnt lgkmcnt(0)" ::: "memory");
        __builtin_amdgcn_sched_barrier(0);
        asm volatile("s_barrier" ::: "memory");
        __builtin_amdgcn_sched_barrier(0);

        // ---- phase 1: stage A-lo(t+2) [cur buf, now dead]; quad (0,1)
        if (t + 2 < 16) STAGE(0, 0, t + 2);
        __builtin_amdgcn_sched_barrier(0);
        __builtin_amdgcn_s_setprio(1);
        QUAD(0, 2)
        __builtin_amdgcn_s_setprio(0);
        __builtin_amdgcn_sched_barrier(0);
        asm volatile("s_barrier" ::: "memory");
        __builtin_amdgcn_sched_barrier(0);

        // ---- phase 2: stage A-hi(t+2); quad (1,0)
        if (t + 2 < 16) STAGE(0, 1, t + 2);
        __builtin_amdgcn_sched_barrier(0);
        __builtin_amdgcn_s_setprio(1);
        QUAD(4, 0)
        __builtin_amdgcn_s_setprio(0);
        __builtin_amdgcn_sched_barrier(0);
        asm volatile("s_barrier" ::: "memory");
        __builtin_amdgcn_sched_barrier(0);

        // ---- phase 3: stage B-lo(t+2); quad (1,1); counted vmcnt
        if (t + 2 < 16) STAGE(1, 0, t + 2);
        __builtin_amdgcn_sched_barrier(0);
        __builtin_amdgcn_s_setprio(1);
        QUAD(4, 2)
        __builtin_amdgcn_s_setprio(0);
        __builtin_amdgcn_sched_barrier(0);
        // steady state: 14 outstanding; oldest 8 = tile t+1's four halves
        if (t < 14)       asm volatile("s_waitcnt vmcnt(6)" ::: "memory");
        else if (t == 14) asm volatile("s_waitcnt vmcnt(0)" ::: "memory");
        asm volatile("s_barrier" ::: "memory");
    }
#undef QUAD
#undef STAGE

    if constexpr (STATS) {
        // per-lane columns: n0 + wn*64 + nf*16 + r16
        float bnf[4];
#pragma unroll
        for (int nf = 0; nf < 4; ++nf)
            bnf[nf] = biasAll[n0 + wn * 64 + nf * 16 + r16];
        float2* lds2 = (float2*)smem;   // [256 rows][4 wn-chunks], 8 KiB
#pragma unroll
        for (int mf = 0; mf < 8; ++mf) {
#pragma unroll
            for (int r = 0; r < 4; ++r) {
                float sv = 0.f, s2v = 0.f;
#pragma unroll
                for (int nf = 0; nf < 4; ++nf) {
                    // bf16-round first: stats must describe the values
                    // gemm_final reads back from C.
                    float v = bf2f(f2bf(acc[mf][nf][r])) + bnf[nf];
                    sv += v; s2v += v * v;
                }
                sv += __shfl_xor(sv, 8);  s2v += __shfl_xor(s2v, 8);
                sv += __shfl_xor(sv, 4);  s2v += __shfl_xor(s2v, 4);
                sv += __shfl_xor(sv, 2);  s2v += __shfl_xor(s2v, 2);
                sv += __shfl_xor(sv, 1);  s2v += __shfl_xor(s2v, 1);
                if (r16 == 0) {
                    int lr = wm * 128 + mf * 16 + quad * 4 + r;
                    lds2[lr * 4 + wn] = make_float2(sv, s2v);
                }
            }
        }
        __syncthreads();
        if (tid < 256) {
            float2 a0 = lds2[tid * 4 + 0], a1 = lds2[tid * 4 + 1];
            float2 a2 = lds2[tid * 4 + 2], a3 = lds2[tid * 4 + 3];
            partials[(size_t)bn * M + m0 + tid] =
                make_float2(a0.x + a1.x + a2.x + a3.x,
                            a0.y + a1.y + a2.y + a3.y);
        }
        // no barrier needed: C-write below doesn't touch LDS
    }

#pragma unroll
    for (int mf = 0; mf < 8; ++mf) {
#pragma unroll
        for (int nf = 0; nf < 4; ++nf) {
            size_t base = (size_t)(m0 + wm * 128 + mf * 16 + quad * 4) * N
                          + n0 + wn * 64 + nf * 16 + r16;
#pragma unroll
            for (int r = 0; r < 4; ++r)
                C[base + (size_t)r * N] = f2bf(acc[mf][nf][r]);
        }
    }
}

// ---------------------------------------------------------------------------
// ctx LN+GELU
// ---------------------------------------------------------------------------
__global__ __launch_bounds__(256) void ln_ctx_kernel(
    const u16* __restrict__ pre, const float* __restrict__ E_op,
    const float* __restrict__ P_pt, const int* __restrict__ ptype,
    const u16* __restrict__ csm, u16* __restrict__ ctx, int tokOff)
{
    __shared__ float red[8];
    int local = blockIdx.x;
    int token = tokOff + local;
    int b = token >> 11;            // T = 2048
    int pt = ptype[token];
    int tid = threadIdx.x;
    int c = tid * 4;
    int wid = tid >> 6, lane = tid & 63;

    ushort4 xp = *(const ushort4*)&pre[(size_t)local * 1024 + c];
    float4 eo = *(const float4*)&E_op[b * 1024 + c];
    float4 pp = *(const float4*)&P_pt[pt * 1024 + c];
    ushort4 cb4 = *(const ushort4*)&csm[CTX_B + c];
    float x[4];
    x[0] = bf2f(xp.x) + eo.x + pp.x + bf2f(cb4.x);
    x[1] = bf2f(xp.y) + eo.y + pp.y + bf2f(cb4.y);
    x[2] = bf2f(xp.z) + eo.z + pp.z + bf2f(cb4.z);
    x[3] = bf2f(xp.w) + eo.w + pp.w + bf2f(cb4.w);

    float s = x[0] + x[1] + x[2] + x[3];
    float s2 = x[0]*x[0] + x[1]*x[1] + x[2]*x[2] + x[3]*x[3];
    for (int off = 32; off; off >>= 1) { s += __shfl_xor(s, off); s2 += __shfl_xor(s2, off); }
    if (lane == 0) { red[wid] = s; red[4 + wid] = s2; }
    __syncthreads();
    s  = red[0] + red[1] + red[2] + red[3];
    s2 = red[4] + red[5] + red[6] + red[7];
    float mean = s * (1.f / 1024.f);
    float var = fmaxf(s2 * (1.f / 1024.f) - mean * mean, 0.f);
    float rs = rsqrtf(var + 1e-5f);

    ushort4 g4 = *(const ushort4*)&csm[CTX_G + c];
    ushort4 b4 = *(const ushort4*)&csm[CTX_BE + c];
    ushort4 o;
    o.x = f2bf(gelu_f((x[0] - mean) * rs * bf2f(g4.x) + bf2f(b4.x)));
    o.y = f2bf(gelu_f((x[1] - mean) * rs * bf2f(g4.y) + bf2f(b4.y)));
    o.z = f2bf(gelu_f((x[2] - mean) * rs * bf2f(g4.z) + bf2f(b4.z)));
    o.w = f2bf(gelu_f((x[3] - mean) * rs * bf2f(g4.w) + bf2f(b4.w)));
    *(ushort4*)&ctx[(size_t)token * 1024 + c] = o;
}

// ---------------------------------------------------------------------------
// gemm_final: out_pre[ks][Rh][128] = gelu(LN(A))@W2pad^T, K-split by 4.
// A-staging applies (x+bias-mean)*rs*gamma+beta then GELU on the fly.
// ---------------------------------------------------------------------------
__global__ __launch_bounds__(256) void gemm_final(
    const u16* __restrict__ A, const u16* __restrict__ W2pad,
    const float* __restrict__ biasAll, const float* __restrict__ gammaAll,
    const float* __restrict__ betaAll, const float2* __restrict__ stats,
    float* __restrict__ out_pre, int Rh)
{
    __shared__ u16 As[128 * 32];
    __shared__ u16 Bs[128 * 32];
    const int tid = threadIdx.x;
    const int wid = tid >> 6, lane = tid & 63;
    const int m0 = blockIdx.x * 128;
    const int ks = blockIdx.y, kbase = ks * 1024;
    const int mw = (wid >> 1) * 64, nw = (wid & 1) * 64;
    const int quad = lane >> 4, r16 = lane & 15;

    f32x4 acc[4][4] = {};

    const int srow = wid * 32 + (lane >> 2);
    const int scol = (lane & 3) * 8;
    const u16* gB = W2pad + (size_t)srow * 4096 + kbase + scol;
    u16* lB = Bs + wid * 32 * 32;

    const int r0 = tid >> 2;
    const int c8 = (tid & 3) * 8;

    for (int k0 = 0; k0 < 1024; k0 += 32) {
        async_load16(gB + k0, lB);
        async_load16(gB + k0 + (size_t)16 * 4096, lB + 16 * 32);
        int kk = kbase + k0 + c8;
        int sl = kk >> 9;
        float4 bi0 = *(const float4*)&biasAll[kk], bi1 = *(const float4*)&biasAll[kk + 4];
        float4 g0 = *(const float4*)&gammaAll[kk], g1 = *(const float4*)&gammaAll[kk + 4];
        float4 be0 = *(const float4*)&betaAll[kk], be1 = *(const float4*)&betaAll[kk + 4];
        float bb[8] = {bi0.x, bi0.y, bi0.z, bi0.w, bi1.x, bi1.y, bi1.z, bi1.w};
        float gg[8] = {g0.x, g0.y, g0.z, g0.w, g1.x, g1.y, g1.z, g1.w};
        float bt[8] = {be0.x, be0.y, be0.z, be0.w, be1.x, be1.y, be1.z, be1.w};
#pragma unroll
        for (int h = 0; h < 2; ++h) {
            int row = m0 + r0 + h * 64;
            const u16* ap = A + (size_t)row * 4096 + kk;
            ushort4 xa = ((const ushort4*)ap)[0];
            ushort4 xb = ((const ushort4*)ap)[1];
            u16 xr[8]; *(ushort4*)&xr[0] = xa; *(ushort4*)&xr[4] = xb;
            float2 st = stats[row * 8 + sl];
            u16 o[8];
#pragma unroll
            for (int j = 0; j < 8; ++j) {
                float v = (bf2f(xr[j]) + bb[j] - st.x) * st.y * gg[j] + bt[j];
                o[j] = f2bf(gelu_f(v));
            }
            *(uint4*)&As[(h * 64 + r0) * 32 + c8] = *(const uint4*)&o[0];
        }
        __syncthreads();

        bf16x8 af[4], bw[4];
#pragma unroll
        for (int i = 0; i < 4; ++i)
            af[i] = *(const bf16x8*)&As[(mw + i * 16 + r16) * 32 + quad * 8];
#pragma unroll
        for (int j = 0; j < 4; ++j)
            bw[j] = *(const bf16x8*)&Bs[(nw + j * 16 + r16) * 32 + quad * 8];
#pragma unroll
        for (int i = 0; i < 4; ++i)
#pragma unroll
            for (int j = 0; j < 4; ++j)
                acc[i][j] = __builtin_amdgcn_mfma_f32_16x16x32_bf16(
                    af[i], bw[j], acc[i][j], 0, 0, 0);
        __syncthreads();
    }

    float* op = out_pre + (size_t)ks * Rh * 128;
#pragma unroll
    for (int i = 0; i < 4; ++i) {
#pragma unroll
        for (int j = 0; j < 4; ++j) {
            int col = nw + j * 16 + r16;
            size_t base = (size_t)(m0 + mw + i * 16 + quad * 4) * 128 + col;
#pragma unroll
            for (int r = 0; r < 4; ++r)
                op[base + (size_t)r * 128] = acc[i][j][r];
        }
    }
}

// ---------------------------------------------------------------------------
// gather: sum 4 K-split planes of out_pre[ks][Rh][128] + out-bias -> outputs.
// ---------------------------------------------------------------------------
__global__ __launch_bounds__(256) void gather_out(
    const float* __restrict__ out_pre, const u16* __restrict__ csm,
    float* __restrict__ out, int tokOff, int Rh)
{
    int idx = blockIdx.x * 256 + threadIdx.x;
    if (idx >= Rh * 64) return;
    int local = idx >> 6;
    int c = idx & 63;
    int token = tokOff + local;
    size_t P = (size_t)Rh * 128;
    size_t base = (size_t)local * 128;
    int col;
    if (c < 3) col = c;
    else if (c == 63) col = 7 * 16;
    else { int d = c - 3; int p = d / 10; col = (p + 1) * 16 + (d - p * 10); }
    float v = out_pre[base + col] + out_pre[P + base + col]
            + out_pre[2 * P + base + col] + out_pre[3 * P + base + col];
    if (c < 3) {
        out[(size_t)token * 3 + c] = v + bf2f(csm[S_B2 + c]);
    } else if (c == 63) {
        out[1032192 + (size_t)token] = v + bf2f(csm[A_B2]);
    } else {
        int d = c - 3;
        int p = d / 10, o = d - p * 10;
        out[49152 + ((size_t)token * 6 + p) * 10 + o] = v + bf2f(csm[D_B2 + p * 10 + o]);
    }
}

// ---------------------------------------------------------------------------
extern "C" void kernel_launch(void* const* d_in, const int* in_sizes, int n_in,
                              void* d_out, int out_size, void* d_ws, size_t ws_size,
                              hipStream_t stream) {
    const float* hidden    = (const float*)d_in[0];
    const int*   op_type   = (const int*)d_in[1];
    const int*   pt_type   = (const int*)d_in[2];
    const float* op_embed  = (const float*)d_in[3];
    const float* pt_embed  = (const float*)d_in[4];
    const float* pos_embed = (const float*)d_in[5];
    const float* ctx_w     = (const float*)d_in[6];
    const float* sign_w1   = (const float*)d_in[10];
    const float* sign_w2   = (const float*)d_in[14];
    const float* dig_w1    = (const float*)d_in[16];
    const float* dig_b1    = (const float*)d_in[17];
    const float* dig_w2    = (const float*)d_in[20];
    const float* aux_w1    = (const float*)d_in[22];
    const float* aux_w2    = (const float*)d_in[24];

    char* ws = (char*)d_ws;
    u16*    ctxWt    = (u16*)(ws + 0);           //  2,097,152 (later W2pad overlay)
    u16*    BtAll    = (u16*)(ws + 2097152);     //  8,388,608
    float*  E_op     = (float*)(ws + 10485760);  //     32,768
    float*  P_pt     = (float*)(ws + 10518528);  //     40,960
    float*  dbias    = (float*)(ws + 10559488);  //     12,288
    u16*    csm      = (u16*)(ws + 10571776);    //     65,536
    float*  biasAll  = (float*)(ws + 10637312);  //     16,384
    float*  gammaAll = (float*)(ws + 10653696);  //     16,384
    float*  betaAll  = (float*)(ws + 10670080);  //     16,384
    float2* stats    = (float2*)(ws + 10686464); //  1,048,576 (max Rh*8*8)
    u16*    context  = (u16*)(ws + 11735040);    // 33,554,432
    u16*    scratch  = (u16*)(ws + 45289472);    // remainder (head_pre + partials / ctx_pre)
    u16*    W2pad    = ctxWt;
    size_t S = (ws_size > 45289472) ? ws_size - 45289472 : 0;

    int Rc = 16384;
    while ((size_t)Rc * 2048 > S && Rc > 512) Rc >>= 1;
    // head chunk needs Rh*8192 (head_pre) + Rh*128 (partials [16][Rh] float2)
    int Rh = 16384;
    while ((size_t)Rh * 8320 > S && Rh > 256) Rh >>= 1;
    float2* partials = (float2*)((char*)scratch + (size_t)Rh * 8192);

    float* out = (float*)d_out;

    SmallTab tab;
    const float* srcs[15] = { op_embed, pt_embed, pos_embed,
                              (const float*)d_in[7], (const float*)d_in[8], (const float*)d_in[9],
                              (const float*)d_in[11], (const float*)d_in[12], (const float*)d_in[13],
                              (const float*)d_in[15],
                              (const float*)d_in[18], (const float*)d_in[19], (const float*)d_in[21],
                              (const float*)d_in[23], (const float*)d_in[25] };
    const int offs[15] = { OP_E, PT_E, POS_E, CTX_B, CTX_G, CTX_BE,
                           S_B1, S_G, S_BE, S_B2,
                           D_G, D_BE, D_B2, A_B1, A_B2 };
    const int cnts[15] = { 2304, 2560, 1536, 1024, 1024, 1024,
                           512, 512, 512, 3,
                           3072, 3072, 60, 512, 1 };
    for (int i = 0; i < 15; ++i) { tab.src[i] = srcs[i]; tab.off[i] = offs[i]; tab.cnt[i] = cnts[i]; }
    convert_small<<<70, 256, 0, stream>>>(tab, csm);

    transpose_all<<<dim3(32, 32, 9), 256, 0, stream>>>(
        ctx_w, sign_w1, aux_w1, dig_w1, ctxWt, BtAll);
    precompute_bias<<<84, 256, 0, stream>>>(
        ctx_w, dig_w1, op_embed, pt_embed, pos_embed, dig_b1, op_type,
        E_op, P_pt, dbias);
    build_vec<<<16, 256, 0, stream>>>(csm, dbias, biasAll, gammaAll, betaAll);

    // hidden f32 -> bf16, overlaid on the context buffer (rows die chunk-wise
    // exactly when ln_ctx overwrites them, after this chunk's gemm consumed them)
    u16* hbf16 = context;
    convert_hidden<<<8192, 256, 0, stream>>>(hidden, hbf16, 16384 * 1024 / 8);

    // context = gelu(LN(hidden @ ctx_w[:1024] + E_op + P_pt + b))
    for (int t0 = 0; t0 < 16384; t0 += Rc) {
        gemm_8ph<false><<<dim3(Rc / 256, 4), 512, 0, stream>>>(
            hbf16 + (size_t)t0 * 1024, ctxWt, scratch, Rc, 1024, nullptr, nullptr);
        ln_ctx_kernel<<<Rc, 256, 0, stream>>>(
            scratch, E_op, P_pt, pt_type, csm, context, t0);
    }

    // W2pad overlays ctxWt (now dead)
    build_w2pad<<<2048, 256, 0, stream>>>(sign_w2, dig_w2, aux_w2, W2pad);

    // head pipeline per chunk: 8-phase GEMM (+fused LN partials) -> stats_fin
    // -> fused LN+GELU GEMM -> gather
    for (int t0 = 0; t0 < 16384; t0 += Rh) {
        gemm_8ph<true><<<dim3(Rh / 256, 16), 512, 0, stream>>>(
            context + (size_t)t0 * 1024, BtAll, scratch, Rh, 4096,
            biasAll, partials);
        stats_fin<<<(Rh * 8 + 255) / 256, 256, 0, stream>>>(partials, stats, Rh);
        // out_pre overlays this chunk's (now dead) context rows: 4*Rh*128*4 B == Rh*2048 B
        float* out_pre = (float*)(context + (size_t)t0 * 1024);
        gemm_final<<<dim3(Rh / 128, 4), 256, 0, stream>>>(
            scratch, W2pad, biasAll, gammaAll, betaAll, stats, out_pre, Rh);
        gather_out<<<(Rh * 64 + 255) / 256, 256, 0, stream>>>(
            out_pre, csm, out, t0, Rh);
    }
}

// Round 5
// 516.601 us; speedup vs baseline: 1.1241x; 1.0183x over previous
//
#include <hip/hip_runtime.h>
#include <hip/hip_bf16.h>

typedef unsigned short u16;
typedef __attribute__((ext_vector_type(8))) __bf16 bf16x8;
typedef __attribute__((ext_vector_type(4))) float f32x4;

typedef __attribute__((address_space(1))) const void GVoid;
typedef __attribute__((address_space(3))) void LVoid;

__device__ __forceinline__ void async_load16(const u16* g, u16* l) {
    __builtin_amdgcn_global_load_lds((GVoid*)g, (LVoid*)l, 16, 0, 0);
}

__device__ __forceinline__ float bf2f(u16 u) {
    union { unsigned i; float f; } v; v.i = ((unsigned)u) << 16; return v.f;
}
__device__ __forceinline__ u16 f2bf(float f) {
    union { float f; unsigned i; } v; v.f = f;
    unsigned r = (v.i + 0x7FFFu + ((v.i >> 16) & 1u)) >> 16;
    return (u16)r;
}
// tanh-form GELU: gelu = x*(1 - 1/(1+e^{2t})), t=0.79788x+0.035677x^3
__device__ __forceinline__ float gelu_f(float x) {
    float t = x * fmaf(0.0356774081f, x * x, 0.7978845608f);
    float e = __expf(2.0f * t);
    float r = 1.0f / (e + 1.0f);
    return x - x * r;
}

// element offsets inside the canonical small-vector buffer (u16, bf16 values)
#define OP_E   0
#define PT_E   2304
#define POS_E  4864
#define CTX_B  6400
#define CTX_G  7424
#define CTX_BE 8448
#define S_B1   9472
#define S_G    9984
#define S_BE   10496
#define S_B2   11008
#define D_G    11012
#define D_BE   14084
#define D_B2   17156
#define A_B1   17216
#define A_B2   17728

// ---------------------------------------------------------------------------
struct SmallTab {
    const float* src[15];
    int off[15];
    int cnt[15];
};

__global__ __launch_bounds__(256) void convert_small(SmallTab tab, u16* __restrict__ dst)
{
    int idx = blockIdx.x * 256 + threadIdx.x;
#pragma unroll
    for (int e = 0; e < 15; ++e) {
        if (idx < tab.cnt[e]) {
            dst[tab.off[e] + idx] = f2bf(tab.src[e][idx]);
            return;
        }
        idx -= tab.cnt[e];
    }
}

// ---------------------------------------------------------------------------
// hidden f32 -> bf16, 16B/thread streaming.
// ---------------------------------------------------------------------------
__global__ __launch_bounds__(256) void convert_hidden(
    const float* __restrict__ src, u16* __restrict__ dst, int n8)
{
    int i = blockIdx.x * 256 + threadIdx.x;
    if (i >= n8) return;
    const float4* p = (const float4*)(src + (size_t)i * 8);
    float4 a = p[0], b = p[1];
    uint4 o;
    o.x = f2bf(a.x) | ((unsigned)f2bf(a.y) << 16);
    o.y = f2bf(a.z) | ((unsigned)f2bf(a.w) << 16);
    o.z = f2bf(b.x) | ((unsigned)f2bf(b.y) << 16);
    o.w = f2bf(b.z) | ((unsigned)f2bf(b.w) << 16);
    *(uint4*)(dst + (size_t)i * 8) = o;
}

// ---------------------------------------------------------------------------
// Transpose fp32 weights to B^T ([N,K] row-major) bf16.
// ---------------------------------------------------------------------------
__global__ __launch_bounds__(256) void transpose_all(
    const float* __restrict__ ctx_w, const float* __restrict__ sign_w1,
    const float* __restrict__ aux_w1, const float* __restrict__ dig_w1,
    u16* __restrict__ ctxWt, u16* __restrict__ BtAll)
{
    __shared__ u16 tl[32][33];
    int z = blockIdx.z;
    const float* src; u16* dst; size_t srcOff = 0; int srcLd, cols;
    if (z == 8) { src = ctx_w; dst = ctxWt; srcLd = 1024; cols = 1024; }
    else {
        srcLd = 512; cols = 512;
        if (z == 0) src = sign_w1;
        else if (z == 1) src = aux_w1;
        else { src = dig_w1; srcOff = (size_t)(z - 2) * 1280 * 512; }
        dst = BtAll + (size_t)z * 512 * 1024;
    }
    int n0 = blockIdx.x * 32;
    if (n0 >= cols) return;
    int k0 = blockIdx.y * 32;
    int t = threadIdx.x;
    int r = t >> 3;
    int c4 = (t & 7) * 4;
    float4 v = *(const float4*)&src[srcOff + (size_t)(k0 + r) * srcLd + n0 + c4];
    tl[r][c4 + 0] = f2bf(v.x); tl[r][c4 + 1] = f2bf(v.y);
    tl[r][c4 + 2] = f2bf(v.z); tl[r][c4 + 3] = f2bf(v.w);
    __syncthreads();
    ushort4 o;
    o.x = tl[c4 + 0][r]; o.y = tl[c4 + 1][r]; o.z = tl[c4 + 2][r]; o.w = tl[c4 + 3][r];
    *(ushort4*)&dst[(size_t)(n0 + r) * 1024 + k0 + c4] = o;
}

// ---------------------------------------------------------------------------
// Row-bias precompute (fp32 out)
// ---------------------------------------------------------------------------
__global__ __launch_bounds__(256) void precompute_bias(
    const float* __restrict__ ctx_w, const float* __restrict__ dig_w1,
    const float* __restrict__ op_embed, const float* __restrict__ pt_embed,
    const float* __restrict__ pos_embed, const float* __restrict__ dig_b1,
    const int* __restrict__ op_type,
    float* __restrict__ E_op, float* __restrict__ P_pt, float* __restrict__ dbias)
{
    int idx = blockIdx.x * 256 + threadIdx.x;
    if (idx < 8192) {
        int b = idx >> 10, n = idx & 1023;
        const float* e = op_embed + op_type[b] * 256;
        float s = 0.f;
        for (int q = 0; q < 256; ++q)
            s += e[q] * ctx_w[(size_t)(1024 + q) * 1024 + n];
        E_op[idx] = s;
    } else if (idx < 18432) {
        int i = idx - 8192;
        int v = i >> 10, n = i & 1023;
        const float* e = pt_embed + v * 256;
        float s = 0.f;
        for (int q = 0; q < 256; ++q)
            s += e[q] * ctx_w[(size_t)(1280 + q) * 1024 + n];
        P_pt[i] = s;
    } else if (idx < 21504) {
        int i = idx - 18432;
        int p = i >> 9, h = i & 511;
        const float* e = pos_embed + p * 256;
        float s = dig_b1[p * 512 + h];
        for (int q = 0; q < 256; ++q)
            s += e[q] * dig_w1[(size_t)p * 1280 * 512 + (size_t)(1024 + q) * 512 + h];
        dbias[i] = s;
    }
}

// ---------------------------------------------------------------------------
// Unified per-column vectors over the 4096 head_pre columns (fp32).
// ---------------------------------------------------------------------------
__global__ __launch_bounds__(256) void build_vec(
    const u16* __restrict__ csm, const float* __restrict__ dbias,
    float* __restrict__ biasAll, float* __restrict__ gammaAll,
    float* __restrict__ betaAll)
{
    int n = blockIdx.x * 256 + threadIdx.x;   // 0..4095
    float bi, g, be;
    if (n < 512) {
        bi = bf2f(csm[S_B1 + n]); g = bf2f(csm[S_G + n]); be = bf2f(csm[S_BE + n]);
    } else if (n < 1024) {
        bi = bf2f(csm[A_B1 + n - 512]); g = 1.f; be = 0.f;
    } else {
        int h = n - 1024;
        bi = dbias[h]; g = bf2f(csm[D_G + h]); be = bf2f(csm[D_BE + h]);
    }
    biasAll[n] = bi; gammaAll[n] = g; betaAll[n] = be;
}

// ---------------------------------------------------------------------------
// Build block-diagonal W2pad [128, 4096] bf16. Row = r*16+o.
// ---------------------------------------------------------------------------
__global__ __launch_bounds__(256) void build_w2pad(
    const float* __restrict__ sign_w2, const float* __restrict__ dig_w2,
    const float* __restrict__ aux_w2, u16* __restrict__ W2pad)
{
    int idx = blockIdx.x * 256 + threadIdx.x;   // 128*4096
    int row = idx >> 12, k = idx & 4095;
    int r = row >> 4, o = row & 15;
    float v = 0.f;
    if (r == 0) {
        if (o < 3 && k < 512) v = sign_w2[k * 3 + o];
    } else if (r == 7) {
        if (o == 0 && k >= 512 && k < 1024) v = aux_w2[k - 512];
    } else {
        int p = r - 1, lo = 1024 + p * 512;
        if (o < 10 && k >= lo && k < lo + 512) v = dig_w2[(size_t)p * 5120 + (k - lo) * 10 + o];
    }
    W2pad[idx] = f2bf(v);
}

// ---------------------------------------------------------------------------
// stats_fin: combine the two 256-col partials per (row, 512-slice) ->
// (mean, rstd); aux slice (s==1) identity. partials layout: [16][Rh] float2.
// ---------------------------------------------------------------------------
__global__ __launch_bounds__(256) void stats_fin(
    const float2* __restrict__ partials, float2* __restrict__ stats, int Rh)
{
    int i = blockIdx.x * 256 + threadIdx.x;
    if (i >= Rh * 8) return;
    int row = i >> 3, s = i & 7;
    float2 o;
    if (s == 1) {
        o = make_float2(0.f, 1.f);
    } else {
        float2 a = partials[(size_t)(2 * s) * Rh + row];
        float2 b = partials[(size_t)(2 * s + 1) * Rh + row];
        float sm = a.x + b.x, s2 = a.y + b.y;
        float mean = sm * (1.f / 512.f);
        float var = fmaxf(s2 * (1.f / 512.f) - mean * mean, 0.f);
        o = make_float2(mean, rsqrtf(var + 1e-5f));
    }
    stats[i] = o;
}

// ---------------------------------------------------------------------------
// GEMM, 256x256-tile 8-phase schedule (m201 structure, plain HIP).
// C[M,N] = A[M,1024] @ Bt[N,1024]^T, bf16 in/out. M,N % 256 == 0, K = 1024.
//
// 8 waves (2Mx4N), 512 thr, BK=64, LDS 128 KiB = 2 dbuf x {A,B} x 2 half x
// [128 rows][8 granules of 16B], granule slot XOR-swizzled with (row&7) (T2).
// global_load_lds dest is linear; the global SOURCE is inverse-swizzled (the
// same involution), so swizzle is both-sides (rule #21).
// Per K-tile: 4 phases x {stage 1 half-tile, 16 MFMA}, one counted
// s_waitcnt vmcnt(6) per tile (T3/T4: 3 half-tiles always in flight),
// setprio around MFMA clusters (T5). Safety: all 24 frag ds_reads issue in
// phase 0 and are fenced by lgkmcnt(0)+barrier before any phase-1..3 stage
// can overwrite the current buffer.
//
// STATS=true (head GEMM): epilogue computes per-row (sum, sumsq) of
// (bf16-rounded acc + biasAll[col]) over this block's 256 cols.
// NO ATOMICS (round-3 lesson: device-scope atomics = memory-side RMW) and
// NO shfl butterfly (round-4 lesson: 256 cross-lane DS ops/lane with
// 1 block/CU = ~8 us/block-round of un-overlappable epilogue). Instead:
// LDS transpose-reduce in the now-dead smem. Rotated pair indexing
// (pair' = (pair+row)&31) keeps both write and read phases at the
// hardware-minimum bank passes; the rotation needs no inverse because the
// final sum is order-invariant.
// ---------------------------------------------------------------------------
template<bool STATS>
__global__ __launch_bounds__(512) void gemm_8ph(
    const u16* __restrict__ A, const u16* __restrict__ Bt, u16* __restrict__ C,
    int M, int N, const float* __restrict__ biasAll, float2* __restrict__ partials)
{
    __shared__ u16 smem[65536];   // 128 KiB
    const int tid = threadIdx.x;
    const int wid = tid >> 6, lane = tid & 63;
    const int quad = lane >> 4, r16 = lane & 15;
    const int wm = wid >> 2, wn = wid & 3;

    // T1: bijective XCD swizzle (nwg always divisible by 8 here)
    const int Mtiles = M >> 8;
    int flat = blockIdx.x + blockIdx.y * gridDim.x;
    int cpx = (Mtiles * (N >> 8)) >> 3;
    int swz = (flat & 7) * cpx + (flat >> 3);
    int bm = swz % Mtiles, bn = swz / Mtiles;
    const int m0 = bm << 8, n0 = bn << 8;

    // staging geometry: granule g = l*512 + tid; row = g>>3, slot = g&7
    // logical col granule = slot ^ (row&7)  (involution)
    const int rb = tid >> 3;                       // row within 64-row chunk
    const int cx = ((tid & 7) ^ (rb & 7)) * 8;     // inverse-swizzled col (elems)
    const u16* gA = A + (size_t)(m0 + rb) * 1024 + cx;
    const u16* gB = Bt + (size_t)(n0 + rb) * 1024 + cx;

#define STAGE(arr, h, tt) do { \
        u16* _d = smem + ((((tt) & 1) * 2 + (arr)) * 2 + (h)) * 8192 + wid * 512; \
        const u16* _s = ((arr) ? gB : gA) + (size_t)((h) * 128) * 1024 + (tt) * 64; \
        async_load16(_s, _d); \
        async_load16(_s + (size_t)64 * 1024, _d + 4096); \
    } while (0)

    // prologue: tile 0 fully (4 halves), tile 1 first 3 halves -> 14 loads;
    // vmcnt(6) completes exactly tile 0, leaves 3 half-tiles in flight.
    STAGE(0, 0, 0); STAGE(0, 1, 0); STAGE(1, 0, 0); STAGE(1, 1, 0);
    STAGE(0, 0, 1); STAGE(0, 1, 1); STAGE(1, 0, 1);
    asm volatile("s_waitcnt vmcnt(6)" ::: "memory");
    asm volatile("s_barrier" ::: "memory");

    f32x4 acc[8][4] = {};
    const int kx0 = ((quad) ^ (r16 & 7)) * 8;       // ks=0 swizzled slot (elems)
    const int kx1 = ((4 + quad) ^ (r16 & 7)) * 8;   // ks=1

#define QUAD(MF0, NF0) \
        _Pragma("unroll") \
        for (int ks = 0; ks < 2; ++ks) \
            _Pragma("unroll") \
            for (int mi = 0; mi < 4; ++mi) \
                _Pragma("unroll") \
                for (int nj = 0; nj < 2; ++nj) \
                    acc[(MF0) + mi][(NF0) + nj] = \
                        __builtin_amdgcn_mfma_f32_16x16x32_bf16( \
                            afr[(MF0) + mi][ks], bfr[(NF0) + nj][ks], \
                            acc[(MF0) + mi][(NF0) + nj], 0, 0, 0);

    for (int t = 0; t < 16; ++t) {
        const int cur = t & 1;
        const u16* sA = smem + cur * 32768 + wm * 8192 + r16 * 64;
        const u16* sB = smem + cur * 32768 + 16384 + (wn >> 1) * 8192
                        + ((wn & 1) * 64 + r16) * 64;

        // ---- phase 0: stage B-hi(t+1) [nxt buf]; read ALL frags; quad (0,0)
        if (t + 1 < 16) STAGE(1, 1, t + 1);
        bf16x8 afr[8][2], bfr[4][2];
#pragma unroll
        for (int mf = 0; mf < 8; ++mf) {
            afr[mf][0] = *(const bf16x8*)&sA[mf * 1024 + kx0];
            afr[mf][1] = *(const bf16x8*)&sA[mf * 1024 + kx1];
        }
#pragma unroll
        for (int nf = 0; nf < 4; ++nf) {
            bfr[nf][0] = *(const bf16x8*)&sB[nf * 1024 + kx0];
            bfr[nf][1] = *(const bf16x8*)&sB[nf * 1024 + kx1];
        }
        __builtin_amdgcn_s_setprio(1);
        QUAD(0, 0)
        __builtin_amdgcn_s_setprio(0);
        // fence: ALL reads of buf[cur] complete before any wave may issue a
        // stage that overwrites it (phases 1-3)
        asm volatile("s_waitcnt lgkmcnt(0)" ::: "memory");
        __builtin_amdgcn_sched_barrier(0);
        asm volatile("s_barrier" ::: "memory");
        __builtin_amdgcn_sched_barrier(0);

        // ---- phase 1: stage A-lo(t+2) [cur buf, now dead]; quad (0,1)
        if (t + 2 < 16) STAGE(0, 0, t + 2);
        __builtin_amdgcn_sched_barrier(0);
        __builtin_amdgcn_s_setprio(1);
        QUAD(0, 2)
        __builtin_amdgcn_s_setprio(0);
        __builtin_amdgcn_sched_barrier(0);
        asm volatile("s_barrier" ::: "memory");
        __builtin_amdgcn_sched_barrier(0);

        // ---- phase 2: stage A-hi(t+2); quad (1,0)
        if (t + 2 < 16) STAGE(0, 1, t + 2);
        __builtin_amdgcn_sched_barrier(0);
        __builtin_amdgcn_s_setprio(1);
        QUAD(4, 0)
        __builtin_amdgcn_s_setprio(0);
        __builtin_amdgcn_sched_barrier(0);
        asm volatile("s_barrier" ::: "memory");
        __builtin_amdgcn_sched_barrier(0);

        // ---- phase 3: stage B-lo(t+2); quad (1,1); counted vmcnt
        if (t + 2 < 16) STAGE(1, 0, t + 2);
        __builtin_amdgcn_sched_barrier(0);
        __builtin_amdgcn_s_setprio(1);
        QUAD(4, 2)
        __builtin_amdgcn_s_setprio(0);
        __builtin_amdgcn_sched_barrier(0);
        // steady state: 14 outstanding; oldest 8 = tile t+1's four halves
        if (t < 14)       asm volatile("s_waitcnt vmcnt(6)" ::: "memory");
        else if (t == 14) asm volatile("s_waitcnt vmcnt(0)" ::: "memory");
        asm volatile("s_barrier" ::: "memory");
    }
#undef QUAD
#undef STAGE

    if constexpr (STATS) {
        // per-lane columns: n0 + wn*64 + nf*16 + r16
        float bnf[4];
#pragma unroll
        for (int nf = 0; nf < 4; ++nf)
            bnf[nf] = biasAll[n0 + wn * 64 + nf * 16 + r16];
        float2* lds2 = (float2*)smem;   // [256 rows][64 slots] float2 = 128 KiB
        // write: per (mf,r) one float2; slot = wn*16+r16, rotated pair index
        {
            const int s = wn * 16 + r16;
            const int pr = s >> 1, par = s & 1;
#pragma unroll
            for (int mf = 0; mf < 8; ++mf) {
#pragma unroll
                for (int r = 0; r < 4; ++r) {
                    float sv = 0.f, s2v = 0.f;
#pragma unroll
                    for (int nf = 0; nf < 4; ++nf) {
                        // bf16-round first: stats must describe the values
                        // gemm_final reads back from C.
                        float v = bf2f(f2bf(acc[mf][nf][r])) + bnf[nf];
                        sv += v; s2v += v * v;
                    }
                    int lr = wm * 128 + mf * 16 + quad * 4 + r;
                    int pp = ((pr + lr) & 31) * 2 + par;     // rotated slot
                    lds2[lr * 64 + pp] = make_float2(sv, s2v);
                }
            }
        }
        __syncthreads();
        // combine: 512 threads, each sums half a row (32 float2 = 16 b128 reads)
        {
            int row = tid >> 1, half = tid & 1;
            float sv = 0.f, s2v = 0.f;
#pragma unroll
            for (int i = 0; i < 16; ++i) {
                int pp = ((half * 16 + i + row) & 31) * 2;   // same rotation
                f32x4 q = *(const f32x4*)&lds2[row * 64 + pp];
                sv += q[0] + q[2]; s2v += q[1] + q[3];
            }
            sv += __shfl_xor(sv, 1); s2v += __shfl_xor(s2v, 1);
            if (half == 0)
                partials[(size_t)bn * M + m0 + row] = make_float2(sv, s2v);
        }
        // no barrier needed: C-write below doesn't touch LDS
    }

#pragma unroll
    for (int mf = 0; mf < 8; ++mf) {
#pragma unroll
        for (int nf = 0; nf < 4; ++nf) {
            size_t base = (size_t)(m0 + wm * 128 + mf * 16 + quad * 4) * N
                          + n0 + wn * 64 + nf * 16 + r16;
#pragma unroll
            for (int r = 0; r < 4; ++r)
                C[base + (size_t)r * N] = f2bf(acc[mf][nf][r]);
        }
    }
}

// ---------------------------------------------------------------------------
// ctx LN+GELU
// ---------------------------------------------------------------------------
__global__ __launch_bounds__(256) void ln_ctx_kernel(
    const u16* __restrict__ pre, const float* __restrict__ E_op,
    const float* __restrict__ P_pt, const int* __restrict__ ptype,
    const u16* __restrict__ csm, u16* __restrict__ ctx, int tokOff)
{
    __shared__ float red[8];
    int local = blockIdx.x;
    int token = tokOff + local;
    int b = token >> 11;            // T = 2048
    int pt = ptype[token];
    int tid = threadIdx.x;
    int c = tid * 4;
    int wid = tid >> 6, lane = tid & 63;

    ushort4 xp = *(const ushort4*)&pre[(size_t)local * 1024 + c];
    float4 eo = *(const float4*)&E_op[b * 1024 + c];
    float4 pp = *(const float4*)&P_pt[pt * 1024 + c];
    ushort4 cb4 = *(const ushort4*)&csm[CTX_B + c];
    float x[4];
    x[0] = bf2f(xp.x) + eo.x + pp.x + bf2f(cb4.x);
    x[1] = bf2f(xp.y) + eo.y + pp.y + bf2f(cb4.y);
    x[2] = bf2f(xp.z) + eo.z + pp.z + bf2f(cb4.z);
    x[3] = bf2f(xp.w) + eo.w + pp.w + bf2f(cb4.w);

    float s = x[0] + x[1] + x[2] + x[3];
    float s2 = x[0]*x[0] + x[1]*x[1] + x[2]*x[2] + x[3]*x[3];
    for (int off = 32; off; off >>= 1) { s += __shfl_xor(s, off); s2 += __shfl_xor(s2, off); }
    if (lane == 0) { red[wid] = s; red[4 + wid] = s2; }
    __syncthreads();
    s  = red[0] + red[1] + red[2] + red[3];
    s2 = red[4] + red[5] + red[6] + red[7];
    float mean = s * (1.f / 1024.f);
    float var = fmaxf(s2 * (1.f / 1024.f) - mean * mean, 0.f);
    float rs = rsqrtf(var + 1e-5f);

    ushort4 g4 = *(const ushort4*)&csm[CTX_G + c];
    ushort4 b4 = *(const ushort4*)&csm[CTX_BE + c];
    ushort4 o;
    o.x = f2bf(gelu_f((x[0] - mean) * rs * bf2f(g4.x) + bf2f(b4.x)));
    o.y = f2bf(gelu_f((x[1] - mean) * rs * bf2f(g4.y) + bf2f(b4.y)));
    o.z = f2bf(gelu_f((x[2] - mean) * rs * bf2f(g4.z) + bf2f(b4.z)));
    o.w = f2bf(gelu_f((x[3] - mean) * rs * bf2f(g4.w) + bf2f(b4.w)));
    *(ushort4*)&ctx[(size_t)token * 1024 + c] = o;
}

// ---------------------------------------------------------------------------
// gemm_final: out_pre[ks][Rh][128] = gelu(LN(A))@W2pad^T, K-split by 4.
// A-staging applies (x+bias-mean)*rs*gamma+beta then GELU on the fly.
// ---------------------------------------------------------------------------
__global__ __launch_bounds__(256) void gemm_final(
    const u16* __restrict__ A, const u16* __restrict__ W2pad,
    const float* __restrict__ biasAll, const float* __restrict__ gammaAll,
    const float* __restrict__ betaAll, const float2* __restrict__ stats,
    float* __restrict__ out_pre, int Rh)
{
    __shared__ u16 As[128 * 32];
    __shared__ u16 Bs[128 * 32];
    const int tid = threadIdx.x;
    const int wid = tid >> 6, lane = tid & 63;
    const int m0 = blockIdx.x * 128;
    const int ks = blockIdx.y, kbase = ks * 1024;
    const int mw = (wid >> 1) * 64, nw = (wid & 1) * 64;
    const int quad = lane >> 4, r16 = lane & 15;

    f32x4 acc[4][4] = {};

    const int srow = wid * 32 + (lane >> 2);
    const int scol = (lane & 3) * 8;
    const u16* gB = W2pad + (size_t)srow * 4096 + kbase + scol;
    u16* lB = Bs + wid * 32 * 32;

    const int r0 = tid >> 2;
    const int c8 = (tid & 3) * 8;

    for (int k0 = 0; k0 < 1024; k0 += 32) {
        async_load16(gB + k0, lB);
        async_load16(gB + k0 + (size_t)16 * 4096, lB + 16 * 32);
        int kk = kbase + k0 + c8;
        int sl = kk >> 9;
        float4 bi0 = *(const float4*)&biasAll[kk], bi1 = *(const float4*)&biasAll[kk + 4];
        float4 g0 = *(const float4*)&gammaAll[kk], g1 = *(const float4*)&gammaAll[kk + 4];
        float4 be0 = *(const float4*)&betaAll[kk], be1 = *(const float4*)&betaAll[kk + 4];
        float bb[8] = {bi0.x, bi0.y, bi0.z, bi0.w, bi1.x, bi1.y, bi1.z, bi1.w};
        float gg[8] = {g0.x, g0.y, g0.z, g0.w, g1.x, g1.y, g1.z, g1.w};
        float bt[8] = {be0.x, be0.y, be0.z, be0.w, be1.x, be1.y, be1.z, be1.w};
#pragma unroll
        for (int h = 0; h < 2; ++h) {
            int row = m0 + r0 + h * 64;
            const u16* ap = A + (size_t)row * 4096 + kk;
            ushort4 xa = ((const ushort4*)ap)[0];
            ushort4 xb = ((const ushort4*)ap)[1];
            u16 xr[8]; *(ushort4*)&xr[0] = xa; *(ushort4*)&xr[4] = xb;
            float2 st = stats[row * 8 + sl];
            u16 o[8];
#pragma unroll
            for (int j = 0; j < 8; ++j) {
                float v = (bf2f(xr[j]) + bb[j] - st.x) * st.y * gg[j] + bt[j];
                o[j] = f2bf(gelu_f(v));
            }
            *(uint4*)&As[(h * 64 + r0) * 32 + c8] = *(const uint4*)&o[0];
        }
        __syncthreads();

        bf16x8 af[4], bw[4];
#pragma unroll
        for (int i = 0; i < 4; ++i)
            af[i] = *(const bf16x8*)&As[(mw + i * 16 + r16) * 32 + quad * 8];
#pragma unroll
        for (int j = 0; j < 4; ++j)
            bw[j] = *(const bf16x8*)&Bs[(nw + j * 16 + r16) * 32 + quad * 8];
#pragma unroll
        for (int i = 0; i < 4; ++i)
#pragma unroll
            for (int j = 0; j < 4; ++j)
                acc[i][j] = __builtin_amdgcn_mfma_f32_16x16x32_bf16(
                    af[i], bw[j], acc[i][j], 0, 0, 0);
        __syncthreads();
    }

    float* op = out_pre + (size_t)ks * Rh * 128;
#pragma unroll
    for (int i = 0; i < 4; ++i) {
#pragma unroll
        for (int j = 0; j < 4; ++j) {
            int col = nw + j * 16 + r16;
            size_t base = (size_t)(m0 + mw + i * 16 + quad * 4) * 128 + col;
#pragma unroll
            for (int r = 0; r < 4; ++r)
                op[base + (size_t)r * 128] = acc[i][j][r];
        }
    }
}

// ---------------------------------------------------------------------------
// gather: sum 4 K-split planes of out_pre[ks][Rh][128] + out-bias -> outputs.
// ---------------------------------------------------------------------------
__global__ __launch_bounds__(256) void gather_out(
    const float* __restrict__ out_pre, const u16* __restrict__ csm,
    float* __restrict__ out, int tokOff, int Rh)
{
    int idx = blockIdx.x * 256 + threadIdx.x;
    if (idx >= Rh * 64) return;
    int local = idx >> 6;
    int c = idx & 63;
    int token = tokOff + local;
    size_t P = (size_t)Rh * 128;
    size_t base = (size_t)local * 128;
    int col;
    if (c < 3) col = c;
    else if (c == 63) col = 7 * 16;
    else { int d = c - 3; int p = d / 10; col = (p + 1) * 16 + (d - p * 10); }
    float v = out_pre[base + col] + out_pre[P + base + col]
            + out_pre[2 * P + base + col] + out_pre[3 * P + base + col];
    if (c < 3) {
        out[(size_t)token * 3 + c] = v + bf2f(csm[S_B2 + c]);
    } else if (c == 63) {
        out[1032192 + (size_t)token] = v + bf2f(csm[A_B2]);
    } else {
        int d = c - 3;
        int p = d / 10, o = d - p * 10;
        out[49152 + ((size_t)token * 6 + p) * 10 + o] = v + bf2f(csm[D_B2 + p * 10 + o]);
    }
}

// ---------------------------------------------------------------------------
extern "C" void kernel_launch(void* const* d_in, const int* in_sizes, int n_in,
                              void* d_out, int out_size, void* d_ws, size_t ws_size,
                              hipStream_t stream) {
    const float* hidden    = (const float*)d_in[0];
    const int*   op_type   = (const int*)d_in[1];
    const int*   pt_type   = (const int*)d_in[2];
    const float* op_embed  = (const float*)d_in[3];
    const float* pt_embed  = (const float*)d_in[4];
    const float* pos_embed = (const float*)d_in[5];
    const float* ctx_w     = (const float*)d_in[6];
    const float* sign_w1   = (const float*)d_in[10];
    const float* sign_w2   = (const float*)d_in[14];
    const float* dig_w1    = (const float*)d_in[16];
    const float* dig_b1    = (const float*)d_in[17];
    const float* dig_w2    = (const float*)d_in[20];
    const float* aux_w1    = (const float*)d_in[22];
    const float* aux_w2    = (const float*)d_in[24];

    char* ws = (char*)d_ws;
    u16*    ctxWt    = (u16*)(ws + 0);           //  2,097,152 (later W2pad overlay)
    u16*    BtAll    = (u16*)(ws + 2097152);     //  8,388,608
    float*  E_op     = (float*)(ws + 10485760);  //     32,768
    float*  P_pt     = (float*)(ws + 10518528);  //     40,960
    float*  dbias    = (float*)(ws + 10559488);  //     12,288
    u16*    csm      = (u16*)(ws + 10571776);    //     65,536
    float*  biasAll  = (float*)(ws + 10637312);  //     16,384
    float*  gammaAll = (float*)(ws + 10653696);  //     16,384
    float*  betaAll  = (float*)(ws + 10670080);  //     16,384
    float2* stats    = (float2*)(ws + 10686464); //  1,048,576 (max Rh*8*8)
    u16*    context  = (u16*)(ws + 11735040);    // 33,554,432
    u16*    scratch  = (u16*)(ws + 45289472);    // remainder (head_pre + partials / ctx_pre)
    u16*    W2pad    = ctxWt;
    size_t S = (ws_size > 45289472) ? ws_size - 45289472 : 0;

    int Rc = 16384;
    while ((size_t)Rc * 2048 > S && Rc > 512) Rc >>= 1;
    // head chunk needs Rh*8192 (head_pre) + Rh*128 (partials [16][Rh] float2)
    int Rh = 16384;
    while ((size_t)Rh * 8320 > S && Rh > 256) Rh >>= 1;
    float2* partials = (float2*)((char*)scratch + (size_t)Rh * 8192);

    float* out = (float*)d_out;

    SmallTab tab;
    const float* srcs[15] = { op_embed, pt_embed, pos_embed,
                              (const float*)d_in[7], (const float*)d_in[8], (const float*)d_in[9],
                              (const float*)d_in[11], (const float*)d_in[12], (const float*)d_in[13],
                              (const float*)d_in[15],
                              (const float*)d_in[18], (const float*)d_in[19], (const float*)d_in[21],
                              (const float*)d_in[23], (const float*)d_in[25] };
    const int offs[15] = { OP_E, PT_E, POS_E, CTX_B, CTX_G, CTX_BE,
                           S_B1, S_G, S_BE, S_B2,
                           D_G, D_BE, D_B2, A_B1, A_B2 };
    const int cnts[15] = { 2304, 2560, 1536, 1024, 1024, 1024,
                           512, 512, 512, 3,
                           3072, 3072, 60, 512, 1 };
    for (int i = 0; i < 15; ++i) { tab.src[i] = srcs[i]; tab.off[i] = offs[i]; tab.cnt[i] = cnts[i]; }
    convert_small<<<70, 256, 0, stream>>>(tab, csm);

    transpose_all<<<dim3(32, 32, 9), 256, 0, stream>>>(
        ctx_w, sign_w1, aux_w1, dig_w1, ctxWt, BtAll);
    precompute_bias<<<84, 256, 0, stream>>>(
        ctx_w, dig_w1, op_embed, pt_embed, pos_embed, dig_b1, op_type,
        E_op, P_pt, dbias);
    build_vec<<<16, 256, 0, stream>>>(csm, dbias, biasAll, gammaAll, betaAll);

    // hidden f32 -> bf16, overlaid on the context buffer (rows die chunk-wise
    // exactly when ln_ctx overwrites them, after this chunk's gemm consumed them)
    u16* hbf16 = context;
    convert_hidden<<<8192, 256, 0, stream>>>(hidden, hbf16, 16384 * 1024 / 8);

    // context = gelu(LN(hidden @ ctx_w[:1024] + E_op + P_pt + b))
    for (int t0 = 0; t0 < 16384; t0 += Rc) {
        gemm_8ph<false><<<dim3(Rc / 256, 4), 512, 0, stream>>>(
            hbf16 + (size_t)t0 * 1024, ctxWt, scratch, Rc, 1024, nullptr, nullptr);
        ln_ctx_kernel<<<Rc, 256, 0, stream>>>(
            scratch, E_op, P_pt, pt_type, csm, context, t0);
    }

    // W2pad overlays ctxWt (now dead)
    build_w2pad<<<2048, 256, 0, stream>>>(sign_w2, dig_w2, aux_w2, W2pad);

    // head pipeline per chunk: 8-phase GEMM (+fused LN partials) -> stats_fin
    // -> fused LN+GELU GEMM -> gather
    for (int t0 = 0; t0 < 16384; t0 += Rh) {
        gemm_8ph<true><<<dim3(Rh / 256, 16), 512, 0, stream>>>(
            context + (size_t)t0 * 1024, BtAll, scratch, Rh, 4096,
            biasAll, partials);
        stats_fin<<<(Rh * 8 + 255) / 256, 256, 0, stream>>>(partials, stats, Rh);
        // out_pre overlays this chunk's (now dead) context rows: 4*Rh*128*4 B == Rh*2048 B
        float* out_pre = (float*)(context + (size_t)t0 * 1024);
        gemm_final<<<dim3(Rh / 128, 4), 256, 0, stream>>>(
            scratch, W2pad, biasAll, gammaAll, betaAll, stats, out_pre, Rh);
        gather_out<<<(Rh * 64 + 255) / 256, 256, 0, stream>>>(
            out_pre, csm, out, t0, Rh);
    }
}

// Round 6
// 511.961 us; speedup vs baseline: 1.1343x; 1.0091x over previous
//
#include <hip/hip_runtime.h>
#include <hip/hip_bf16.h>

typedef unsigned short u16;
typedef __attribute__((ext_vector_type(8))) __bf16 bf16x8;
typedef __attribute__((ext_vector_type(4))) float f32x4;

typedef __attribute__((address_space(1))) const void GVoid;
typedef __attribute__((address_space(3))) void LVoid;

__device__ __forceinline__ void async_load16(const u16* g, u16* l) {
    __builtin_amdgcn_global_load_lds((GVoid*)g, (LVoid*)l, 16, 0, 0);
}

__device__ __forceinline__ float bf2f(u16 u) {
    union { unsigned i; float f; } v; v.i = ((unsigned)u) << 16; return v.f;
}
__device__ __forceinline__ u16 f2bf(float f) {
    union { float f; unsigned i; } v; v.f = f;
    unsigned r = (v.i + 0x7FFFu + ((v.i >> 16) & 1u)) >> 16;
    return (u16)r;
}
// tanh-form GELU: gelu = x*(1 - 1/(1+e^{2t})), t=0.79788x+0.035677x^3
__device__ __forceinline__ float gelu_f(float x) {
    float t = x * fmaf(0.0356774081f, x * x, 0.7978845608f);
    float e = __expf(2.0f * t);
    float r = 1.0f / (e + 1.0f);
    return x - x * r;
}

// element offsets inside the canonical small-vector buffer (u16, bf16 values)
#define OP_E   0
#define PT_E   2304
#define POS_E  4864
#define CTX_B  6400
#define CTX_G  7424
#define CTX_BE 8448
#define S_B1   9472
#define S_G    9984
#define S_BE   10496
#define S_B2   11008
#define D_G    11012
#define D_BE   14084
#define D_B2   17156
#define A_B1   17216
#define A_B2   17728

// ---------------------------------------------------------------------------
struct SmallTab {
    const float* src[15];
    int off[15];
    int cnt[15];
};

__global__ __launch_bounds__(256) void convert_small(SmallTab tab, u16* __restrict__ dst)
{
    int idx = blockIdx.x * 256 + threadIdx.x;
#pragma unroll
    for (int e = 0; e < 15; ++e) {
        if (idx < tab.cnt[e]) {
            dst[tab.off[e] + idx] = f2bf(tab.src[e][idx]);
            return;
        }
        idx -= tab.cnt[e];
    }
}

// ---------------------------------------------------------------------------
// hidden f32 -> bf16, 16B/thread streaming.
// ---------------------------------------------------------------------------
__global__ __launch_bounds__(256) void convert_hidden(
    const float* __restrict__ src, u16* __restrict__ dst, int n8)
{
    int i = blockIdx.x * 256 + threadIdx.x;
    if (i >= n8) return;
    const float4* p = (const float4*)(src + (size_t)i * 8);
    float4 a = p[0], b = p[1];
    uint4 o;
    o.x = f2bf(a.x) | ((unsigned)f2bf(a.y) << 16);
    o.y = f2bf(a.z) | ((unsigned)f2bf(a.w) << 16);
    o.z = f2bf(b.x) | ((unsigned)f2bf(b.y) << 16);
    o.w = f2bf(b.z) | ((unsigned)f2bf(b.w) << 16);
    *(uint4*)(dst + (size_t)i * 8) = o;
}

// ---------------------------------------------------------------------------
// Transpose fp32 weights to B^T ([N,K] row-major) bf16.
// ---------------------------------------------------------------------------
__global__ __launch_bounds__(256) void transpose_all(
    const float* __restrict__ ctx_w, const float* __restrict__ sign_w1,
    const float* __restrict__ aux_w1, const float* __restrict__ dig_w1,
    u16* __restrict__ ctxWt, u16* __restrict__ BtAll)
{
    __shared__ u16 tl[32][33];
    int z = blockIdx.z;
    const float* src; u16* dst; size_t srcOff = 0; int srcLd, cols;
    if (z == 8) { src = ctx_w; dst = ctxWt; srcLd = 1024; cols = 1024; }
    else {
        srcLd = 512; cols = 512;
        if (z == 0) src = sign_w1;
        else if (z == 1) src = aux_w1;
        else { src = dig_w1; srcOff = (size_t)(z - 2) * 1280 * 512; }
        dst = BtAll + (size_t)z * 512 * 1024;
    }
    int n0 = blockIdx.x * 32;
    if (n0 >= cols) return;
    int k0 = blockIdx.y * 32;
    int t = threadIdx.x;
    int r = t >> 3;
    int c4 = (t & 7) * 4;
    float4 v = *(const float4*)&src[srcOff + (size_t)(k0 + r) * srcLd + n0 + c4];
    tl[r][c4 + 0] = f2bf(v.x); tl[r][c4 + 1] = f2bf(v.y);
    tl[r][c4 + 2] = f2bf(v.z); tl[r][c4 + 3] = f2bf(v.w);
    __syncthreads();
    ushort4 o;
    o.x = tl[c4 + 0][r]; o.y = tl[c4 + 1][r]; o.z = tl[c4 + 2][r]; o.w = tl[c4 + 3][r];
    *(ushort4*)&dst[(size_t)(n0 + r) * 1024 + k0 + c4] = o;
}

// ---------------------------------------------------------------------------
// Row-bias precompute (fp32 out)
// ---------------------------------------------------------------------------
__global__ __launch_bounds__(256) void precompute_bias(
    const float* __restrict__ ctx_w, const float* __restrict__ dig_w1,
    const float* __restrict__ op_embed, const float* __restrict__ pt_embed,
    const float* __restrict__ pos_embed, const float* __restrict__ dig_b1,
    const int* __restrict__ op_type,
    float* __restrict__ E_op, float* __restrict__ P_pt, float* __restrict__ dbias)
{
    int idx = blockIdx.x * 256 + threadIdx.x;
    if (idx < 8192) {
        int b = idx >> 10, n = idx & 1023;
        const float* e = op_embed + op_type[b] * 256;
        float s = 0.f;
        for (int q = 0; q < 256; ++q)
            s += e[q] * ctx_w[(size_t)(1024 + q) * 1024 + n];
        E_op[idx] = s;
    } else if (idx < 18432) {
        int i = idx - 8192;
        int v = i >> 10, n = i & 1023;
        const float* e = pt_embed + v * 256;
        float s = 0.f;
        for (int q = 0; q < 256; ++q)
            s += e[q] * ctx_w[(size_t)(1280 + q) * 1024 + n];
        P_pt[i] = s;
    } else if (idx < 21504) {
        int i = idx - 18432;
        int p = i >> 9, h = i & 511;
        const float* e = pos_embed + p * 256;
        float s = dig_b1[p * 512 + h];
        for (int q = 0; q < 256; ++q)
            s += e[q] * dig_w1[(size_t)p * 1280 * 512 + (size_t)(1024 + q) * 512 + h];
        dbias[i] = s;
    }
}

// ---------------------------------------------------------------------------
// Unified per-column vectors over the 4096 head_pre columns (fp32).
// ---------------------------------------------------------------------------
__global__ __launch_bounds__(256) void build_vec(
    const u16* __restrict__ csm, const float* __restrict__ dbias,
    float* __restrict__ biasAll, float* __restrict__ gammaAll,
    float* __restrict__ betaAll)
{
    int n = blockIdx.x * 256 + threadIdx.x;   // 0..4095
    float bi, g, be;
    if (n < 512) {
        bi = bf2f(csm[S_B1 + n]); g = bf2f(csm[S_G + n]); be = bf2f(csm[S_BE + n]);
    } else if (n < 1024) {
        bi = bf2f(csm[A_B1 + n - 512]); g = 1.f; be = 0.f;
    } else {
        int h = n - 1024;
        bi = dbias[h]; g = bf2f(csm[D_G + h]); be = bf2f(csm[D_BE + h]);
    }
    biasAll[n] = bi; gammaAll[n] = g; betaAll[n] = be;
}

// ---------------------------------------------------------------------------
// Build block-diagonal W2pad [128, 4096] bf16. Row = r*16+o.
// ---------------------------------------------------------------------------
__global__ __launch_bounds__(256) void build_w2pad(
    const float* __restrict__ sign_w2, const float* __restrict__ dig_w2,
    const float* __restrict__ aux_w2, u16* __restrict__ W2pad)
{
    int idx = blockIdx.x * 256 + threadIdx.x;   // 128*4096
    int row = idx >> 12, k = idx & 4095;
    int r = row >> 4, o = row & 15;
    float v = 0.f;
    if (r == 0) {
        if (o < 3 && k < 512) v = sign_w2[k * 3 + o];
    } else if (r == 7) {
        if (o == 0 && k >= 512 && k < 1024) v = aux_w2[k - 512];
    } else {
        int p = r - 1, lo = 1024 + p * 512;
        if (o < 10 && k >= lo && k < lo + 512) v = dig_w2[(size_t)p * 5120 + (k - lo) * 10 + o];
    }
    W2pad[idx] = f2bf(v);
}

// ---------------------------------------------------------------------------
// stats_fin: combine the two 256-col partials per (row, 512-slice) ->
// (mean, rstd); aux slice (s==1) identity. partials layout: [16][Rh] float2.
// ---------------------------------------------------------------------------
__global__ __launch_bounds__(256) void stats_fin(
    const float2* __restrict__ partials, float2* __restrict__ stats, int Rh)
{
    int i = blockIdx.x * 256 + threadIdx.x;
    if (i >= Rh * 8) return;
    int row = i >> 3, s = i & 7;
    float2 o;
    if (s == 1) {
        o = make_float2(0.f, 1.f);
    } else {
        float2 a = partials[(size_t)(2 * s) * Rh + row];
        float2 b = partials[(size_t)(2 * s + 1) * Rh + row];
        float sm = a.x + b.x, s2 = a.y + b.y;
        float mean = sm * (1.f / 512.f);
        float var = fmaxf(s2 * (1.f / 512.f) - mean * mean, 0.f);
        o = make_float2(mean, rsqrtf(var + 1e-5f));
    }
    stats[i] = o;
}

// ---------------------------------------------------------------------------
// GEMM, 256x256-tile 8-phase schedule (m201 structure, plain HIP).
// C[M,N] = A[M,1024] @ Bt[N,1024]^T, bf16 in/out. M,N % 256 == 0, K = 1024.
//
// 8 waves (2Mx4N), 512 thr, BK=64, LDS 128 KiB = 2 dbuf x {A,B} x 2 half x
// [128 rows][8 granules of 16B], granule slot XOR-swizzled with (row&7) (T2).
// global_load_lds dest is linear; the global SOURCE is inverse-swizzled (the
// same involution), so swizzle is both-sides (rule #21).
// Per K-tile: 4 phases x {stage 1 half-tile, 16 MFMA}, one counted
// s_waitcnt vmcnt(6) per tile (T3/T4: 3 half-tiles always in flight),
// setprio around MFMA clusters (T5). Safety: all 24 frag ds_reads issue in
// phase 0 and are fenced by lgkmcnt(0)+barrier before any phase-1..3 stage
// can overwrite the current buffer.
//
// STATS=true (head GEMM): f2bf is computed ONCE per element (cv), shared by
// the stats pass and the C-write (round-5 lesson: duplicated f2bf in the
// stats pass was ~10 us of un-overlappable VALU at 1 block/CU). Stats use
// LDS transpose-reduce in the now-dead smem (rounds 3/4 lessons: no
// device-scope atomics, no 256-deep shfl butterflies).
// ---------------------------------------------------------------------------
template<bool STATS>
__global__ __launch_bounds__(512) void gemm_8ph(
    const u16* __restrict__ A, const u16* __restrict__ Bt, u16* __restrict__ C,
    int M, int N, const float* __restrict__ biasAll, float2* __restrict__ partials)
{
    __shared__ u16 smem[65536];   // 128 KiB
    const int tid = threadIdx.x;
    const int wid = tid >> 6, lane = tid & 63;
    const int quad = lane >> 4, r16 = lane & 15;
    const int wm = wid >> 2, wn = wid & 3;

    // T1: bijective XCD swizzle (nwg always divisible by 8 here)
    const int Mtiles = M >> 8;
    int flat = blockIdx.x + blockIdx.y * gridDim.x;
    int cpx = (Mtiles * (N >> 8)) >> 3;
    int swz = (flat & 7) * cpx + (flat >> 3);
    int bm = swz % Mtiles, bn = swz / Mtiles;
    const int m0 = bm << 8, n0 = bn << 8;

    // staging geometry: granule g = l*512 + tid; row = g>>3, slot = g&7
    // logical col granule = slot ^ (row&7)  (involution)
    const int rb = tid >> 3;                       // row within 64-row chunk
    const int cx = ((tid & 7) ^ (rb & 7)) * 8;     // inverse-swizzled col (elems)
    const u16* gA = A + (size_t)(m0 + rb) * 1024 + cx;
    const u16* gB = Bt + (size_t)(n0 + rb) * 1024 + cx;

#define STAGE(arr, h, tt) do { \
        u16* _d = smem + ((((tt) & 1) * 2 + (arr)) * 2 + (h)) * 8192 + wid * 512; \
        const u16* _s = ((arr) ? gB : gA) + (size_t)((h) * 128) * 1024 + (tt) * 64; \
        async_load16(_s, _d); \
        async_load16(_s + (size_t)64 * 1024, _d + 4096); \
    } while (0)

    // prologue: tile 0 fully (4 halves), tile 1 first 3 halves -> 14 loads;
    // vmcnt(6) completes exactly tile 0, leaves 3 half-tiles in flight.
    STAGE(0, 0, 0); STAGE(0, 1, 0); STAGE(1, 0, 0); STAGE(1, 1, 0);
    STAGE(0, 0, 1); STAGE(0, 1, 1); STAGE(1, 0, 1);
    asm volatile("s_waitcnt vmcnt(6)" ::: "memory");
    asm volatile("s_barrier" ::: "memory");

    f32x4 acc[8][4] = {};
    const int kx0 = ((quad) ^ (r16 & 7)) * 8;       // ks=0 swizzled slot (elems)
    const int kx1 = ((4 + quad) ^ (r16 & 7)) * 8;   // ks=1

#define QUAD(MF0, NF0) \
        _Pragma("unroll") \
        for (int ks = 0; ks < 2; ++ks) \
            _Pragma("unroll") \
            for (int mi = 0; mi < 4; ++mi) \
                _Pragma("unroll") \
                for (int nj = 0; nj < 2; ++nj) \
                    acc[(MF0) + mi][(NF0) + nj] = \
                        __builtin_amdgcn_mfma_f32_16x16x32_bf16( \
                            afr[(MF0) + mi][ks], bfr[(NF0) + nj][ks], \
                            acc[(MF0) + mi][(NF0) + nj], 0, 0, 0);

    for (int t = 0; t < 16; ++t) {
        const int cur = t & 1;
        const u16* sA = smem + cur * 32768 + wm * 8192 + r16 * 64;
        const u16* sB = smem + cur * 32768 + 16384 + (wn >> 1) * 8192
                        + ((wn & 1) * 64 + r16) * 64;

        // ---- phase 0: stage B-hi(t+1) [nxt buf]; read ALL frags; quad (0,0)
        if (t + 1 < 16) STAGE(1, 1, t + 1);
        bf16x8 afr[8][2], bfr[4][2];
#pragma unroll
        for (int mf = 0; mf < 8; ++mf) {
            afr[mf][0] = *(const bf16x8*)&sA[mf * 1024 + kx0];
            afr[mf][1] = *(const bf16x8*)&sA[mf * 1024 + kx1];
        }
#pragma unroll
        for (int nf = 0; nf < 4; ++nf) {
            bfr[nf][0] = *(const bf16x8*)&sB[nf * 1024 + kx0];
            bfr[nf][1] = *(const bf16x8*)&sB[nf * 1024 + kx1];
        }
        __builtin_amdgcn_s_setprio(1);
        QUAD(0, 0)
        __builtin_amdgcn_s_setprio(0);
        // fence: ALL reads of buf[cur] complete before any wave may issue a
        // stage that overwrites it (phases 1-3)
        asm volatile("s_waitcnt lgkmcnt(0)" ::: "memory");
        __builtin_amdgcn_sched_barrier(0);
        asm volatile("s_barrier" ::: "memory");
        __builtin_amdgcn_sched_barrier(0);

        // ---- phase 1: stage A-lo(t+2) [cur buf, now dead]; quad (0,1)
        if (t + 2 < 16) STAGE(0, 0, t + 2);
        __builtin_amdgcn_sched_barrier(0);
        __builtin_amdgcn_s_setprio(1);
        QUAD(0, 2)
        __builtin_amdgcn_s_setprio(0);
        __builtin_amdgcn_sched_barrier(0);
        asm volatile("s_barrier" ::: "memory");
        __builtin_amdgcn_sched_barrier(0);

        // ---- phase 2: stage A-hi(t+2); quad (1,0)
        if (t + 2 < 16) STAGE(0, 1, t + 2);
        __builtin_amdgcn_sched_barrier(0);
        __builtin_amdgcn_s_setprio(1);
        QUAD(4, 0)
        __builtin_amdgcn_s_setprio(0);
        __builtin_amdgcn_sched_barrier(0);
        asm volatile("s_barrier" ::: "memory");
        __builtin_amdgcn_sched_barrier(0);

        // ---- phase 3: stage B-lo(t+2); quad (1,1); counted vmcnt
        if (t + 2 < 16) STAGE(1, 0, t + 2);
        __builtin_amdgcn_sched_barrier(0);
        __builtin_amdgcn_s_setprio(1);
        QUAD(4, 2)
        __builtin_amdgcn_s_setprio(0);
        __builtin_amdgcn_sched_barrier(0);
        // steady state: 14 outstanding; oldest 8 = tile t+1's four halves
        if (t < 14)       asm volatile("s_waitcnt vmcnt(6)" ::: "memory");
        else if (t == 14) asm volatile("s_waitcnt vmcnt(0)" ::: "memory");
        asm volatile("s_barrier" ::: "memory");
    }
#undef QUAD
#undef STAGE

    // epilogue: per-mf group, convert once (cv), optional stats, C-write.
    float bnf[4];
    float2* lds2 = (float2*)smem;   // [256 rows][64 slots] float2 (dead smem)
    int sstat = 0, prp = 0, parp = 0;
    if constexpr (STATS) {
#pragma unroll
        for (int nf = 0; nf < 4; ++nf)
            bnf[nf] = biasAll[n0 + wn * 64 + nf * 16 + r16];
        sstat = wn * 16 + r16; prp = sstat >> 1; parp = sstat & 1;
    }
#pragma unroll
    for (int mf = 0; mf < 8; ++mf) {
        u16 cvm[4][4];
#pragma unroll
        for (int nf = 0; nf < 4; ++nf)
#pragma unroll
            for (int r = 0; r < 4; ++r)
                cvm[nf][r] = f2bf(acc[mf][nf][r]);
        if constexpr (STATS) {
#pragma unroll
            for (int r = 0; r < 4; ++r) {
                float sv = 0.f, s2v = 0.f;
#pragma unroll
                for (int nf = 0; nf < 4; ++nf) {
                    float v = bf2f(cvm[nf][r]) + bnf[nf];
                    sv += v; s2v += v * v;
                }
                int lr = wm * 128 + mf * 16 + quad * 4 + r;
                int pp = ((prp + lr) & 31) * 2 + parp;     // rotated slot
                lds2[lr * 64 + pp] = make_float2(sv, s2v);
            }
        }
#pragma unroll
        for (int nf = 0; nf < 4; ++nf) {
            size_t base = (size_t)(m0 + wm * 128 + mf * 16 + quad * 4) * N
                          + n0 + wn * 64 + nf * 16 + r16;
#pragma unroll
            for (int r = 0; r < 4; ++r)
                C[base + (size_t)r * N] = cvm[nf][r];
        }
    }
    if constexpr (STATS) {
        __syncthreads();
        // combine: 512 threads, each sums half a row (32 float2 = 16 b128 reads)
        int row = tid >> 1, half = tid & 1;
        float sv = 0.f, s2v = 0.f;
#pragma unroll
        for (int i = 0; i < 16; ++i) {
            int pp = ((half * 16 + i + row) & 31) * 2;   // same rotation
            f32x4 q = *(const f32x4*)&lds2[row * 64 + pp];
            sv += q[0] + q[2]; s2v += q[1] + q[3];
        }
        sv += __shfl_xor(sv, 1); s2v += __shfl_xor(s2v, 1);
        if (half == 0)
            partials[(size_t)bn * M + m0 + row] = make_float2(sv, s2v);
    }
}

// ---------------------------------------------------------------------------
// ctx LN+GELU
// ---------------------------------------------------------------------------
__global__ __launch_bounds__(256) void ln_ctx_kernel(
    const u16* __restrict__ pre, const float* __restrict__ E_op,
    const float* __restrict__ P_pt, const int* __restrict__ ptype,
    const u16* __restrict__ csm, u16* __restrict__ ctx, int tokOff)
{
    __shared__ float red[8];
    int local = blockIdx.x;
    int token = tokOff + local;
    int b = token >> 11;            // T = 2048
    int pt = ptype[token];
    int tid = threadIdx.x;
    int c = tid * 4;
    int wid = tid >> 6, lane = tid & 63;

    ushort4 xp = *(const ushort4*)&pre[(size_t)local * 1024 + c];
    float4 eo = *(const float4*)&E_op[b * 1024 + c];
    float4 pp = *(const float4*)&P_pt[pt * 1024 + c];
    ushort4 cb4 = *(const ushort4*)&csm[CTX_B + c];
    float x[4];
    x[0] = bf2f(xp.x) + eo.x + pp.x + bf2f(cb4.x);
    x[1] = bf2f(xp.y) + eo.y + pp.y + bf2f(cb4.y);
    x[2] = bf2f(xp.z) + eo.z + pp.z + bf2f(cb4.z);
    x[3] = bf2f(xp.w) + eo.w + pp.w + bf2f(cb4.w);

    float s = x[0] + x[1] + x[2] + x[3];
    float s2 = x[0]*x[0] + x[1]*x[1] + x[2]*x[2] + x[3]*x[3];
    for (int off = 32; off; off >>= 1) { s += __shfl_xor(s, off); s2 += __shfl_xor(s2, off); }
    if (lane == 0) { red[wid] = s; red[4 + wid] = s2; }
    __syncthreads();
    s  = red[0] + red[1] + red[2] + red[3];
    s2 = red[4] + red[5] + red[6] + red[7];
    float mean = s * (1.f / 1024.f);
    float var = fmaxf(s2 * (1.f / 1024.f) - mean * mean, 0.f);
    float rs = rsqrtf(var + 1e-5f);

    ushort4 g4 = *(const ushort4*)&csm[CTX_G + c];
    ushort4 b4 = *(const ushort4*)&csm[CTX_BE + c];
    ushort4 o;
    o.x = f2bf(gelu_f((x[0] - mean) * rs * bf2f(g4.x) + bf2f(b4.x)));
    o.y = f2bf(gelu_f((x[1] - mean) * rs * bf2f(g4.y) + bf2f(b4.y)));
    o.z = f2bf(gelu_f((x[2] - mean) * rs * bf2f(g4.z) + bf2f(b4.z)));
    o.w = f2bf(gelu_f((x[3] - mean) * rs * bf2f(g4.w) + bf2f(b4.w)));
    *(ushort4*)&ctx[(size_t)token * 1024 + c] = o;
}

// ---------------------------------------------------------------------------
// gemm_final_fused: out = (gelu(LN(A)) @ W2pad^T + out-bias) scattered
// directly into the three output regions. Full K=4096 per block (no K-split,
// no out_pre round-trip, no gather kernel).
//
// M-tile 64, 512 threads (8 waves, wave n-column cg = wid), BK=64, 128 K-steps
// as 8 sl-slices x 8 sub-steps (stats st uniform per sl — static indexing,
// rule #20). A-staging applies LN+GELU in-register with a one-step A-reg
// prefetch; As writes XOR-swizzled, Bs staged via global_load_lds with
// inverse-swizzled SOURCE (rule #21) so frag reads are conflict-free.
// W2pad (1 MB) is read by every block -> L2-resident.
// ---------------------------------------------------------------------------
__global__ __launch_bounds__(512) void gemm_final_fused(
    const u16* __restrict__ A, const u16* __restrict__ W2pad,
    const float* __restrict__ biasAll, const float* __restrict__ gammaAll,
    const float* __restrict__ betaAll, const float2* __restrict__ stats,
    const u16* __restrict__ csm, float* __restrict__ out, int tokOff)
{
    __shared__ u16 As[64 * 64];     //  8 KiB
    __shared__ u16 Bs[128 * 64];    // 16 KiB
    const int tid = threadIdx.x;
    const int wid = tid >> 6, lane = tid & 63;
    const int quad = lane >> 4, r16 = lane & 15;
    const int m0 = blockIdx.x * 64;

    // A staging: row r0, logical granule lg (8 elems), swizzled phys granule
    const int r0 = tid >> 3;
    const int lg = tid & 7;
    const int c8 = lg * 8;
    const int pgA = ((lg ^ (r0 & 7)) * 8);
    const u16* arow = A + (size_t)(m0 + r0) * 4096;

    // B staging: 2 calls; call h covers rows h*64 + (tid>>3); source granule
    // inverse-swizzled so linear LDS dest yields swizzled logical layout.
    const int bcol = ((tid & 7) ^ (r0 & 7)) * 8;
    const u16* brow = W2pad + (size_t)r0 * 4096 + bcol;

    f32x4 acc[4] = {};

    uint4 xa = *(const uint4*)(arow + c8);      // prefetch k0 = 0

    for (int sl = 0; sl < 8; ++sl) {
        const float2 st = stats[(m0 + r0) * 8 + sl];
        for (int kb = 0; kb < 8; ++kb) {
            const int k0 = sl * 512 + kb * 64;
            // stage B[128][64] (2 x 8KB calls, linear dest)
            async_load16(brow + k0, Bs + tid * 8);
            async_load16(brow + (size_t)64 * 4096 + k0, Bs + 4096 + tid * 8);
            // prefetch next A chunk
            uint4 xn = xa;
            if (k0 + 64 < 4096) xn = *(const uint4*)(arow + k0 + 64 + c8);
            // LN+GELU on current 8 elems
            const int kk = k0 + c8;
            float4 bi0 = *(const float4*)&biasAll[kk],  bi1 = *(const float4*)&biasAll[kk + 4];
            float4 g0  = *(const float4*)&gammaAll[kk], g1  = *(const float4*)&gammaAll[kk + 4];
            float4 be0 = *(const float4*)&betaAll[kk],  be1 = *(const float4*)&betaAll[kk + 4];
            float bb[8] = {bi0.x, bi0.y, bi0.z, bi0.w, bi1.x, bi1.y, bi1.z, bi1.w};
            float gg[8] = {g0.x, g0.y, g0.z, g0.w, g1.x, g1.y, g1.z, g1.w};
            float bt[8] = {be0.x, be0.y, be0.z, be0.w, be1.x, be1.y, be1.z, be1.w};
            u16 xr[8]; *(uint4*)&xr[0] = xa;
            u16 o[8];
#pragma unroll
            for (int j = 0; j < 8; ++j) {
                float v = (bf2f(xr[j]) + bb[j] - st.x) * st.y * gg[j] + bt[j];
                o[j] = f2bf(gelu_f(v));
            }
            *(uint4*)&As[r0 * 64 + pgA] = *(const uint4*)&o[0];
            __syncthreads();

            bf16x8 af[4][2], bw[2];
#pragma unroll
            for (int ks = 0; ks < 2; ++ks) {
                int pg = ((ks * 4 + quad) ^ (r16 & 7)) * 8;
#pragma unroll
                for (int i = 0; i < 4; ++i)
                    af[i][ks] = *(const bf16x8*)&As[(i * 16 + r16) * 64 + pg];
                bw[ks] = *(const bf16x8*)&Bs[(wid * 16 + r16) * 64 + pg];
            }
#pragma unroll
            for (int ks = 0; ks < 2; ++ks)
#pragma unroll
                for (int i = 0; i < 4; ++i)
                    acc[i] = __builtin_amdgcn_mfma_f32_16x16x32_bf16(
                        af[i][ks], bw[ks], acc[i], 0, 0, 0);
            __syncthreads();
            xa = xn;
        }
    }

    // scatter epilogue: wave wid owns output-col group cg = wid, o = r16
    const int cg = wid, o = r16;
    int mode = -1; float obias = 0.f;
    if (cg == 0)      { if (o < 3)  { mode = 0; obias = bf2f(csm[S_B2 + o]); } }
    else if (cg == 7) { if (o == 0) { mode = 2; obias = bf2f(csm[A_B2]); } }
    else              { if (o < 10) { mode = 1; obias = bf2f(csm[D_B2 + (cg - 1) * 10 + o]); } }
    if (mode >= 0) {
#pragma unroll
        for (int i = 0; i < 4; ++i)
#pragma unroll
            for (int r = 0; r < 4; ++r) {
                int token = tokOff + m0 + i * 16 + quad * 4 + r;
                float v = acc[i][r] + obias;
                if (mode == 0)      out[(size_t)token * 3 + o] = v;
                else if (mode == 1) out[49152 + ((size_t)token * 6 + (cg - 1)) * 10 + o] = v;
                else                out[1032192 + (size_t)token] = v;
            }
    }
}

// ---------------------------------------------------------------------------
extern "C" void kernel_launch(void* const* d_in, const int* in_sizes, int n_in,
                              void* d_out, int out_size, void* d_ws, size_t ws_size,
                              hipStream_t stream) {
    const float* hidden    = (const float*)d_in[0];
    const int*   op_type   = (const int*)d_in[1];
    const int*   pt_type   = (const int*)d_in[2];
    const float* op_embed  = (const float*)d_in[3];
    const float* pt_embed  = (const float*)d_in[4];
    const float* pos_embed = (const float*)d_in[5];
    const float* ctx_w     = (const float*)d_in[6];
    const float* sign_w1   = (const float*)d_in[10];
    const float* sign_w2   = (const float*)d_in[14];
    const float* dig_w1    = (const float*)d_in[16];
    const float* dig_b1    = (const float*)d_in[17];
    const float* dig_w2    = (const float*)d_in[20];
    const float* aux_w1    = (const float*)d_in[22];
    const float* aux_w2    = (const float*)d_in[24];

    char* ws = (char*)d_ws;
    u16*    ctxWt    = (u16*)(ws + 0);           //  2,097,152 (later W2pad overlay)
    u16*    BtAll    = (u16*)(ws + 2097152);     //  8,388,608
    float*  E_op     = (float*)(ws + 10485760);  //     32,768
    float*  P_pt     = (float*)(ws + 10518528);  //     40,960
    float*  dbias    = (float*)(ws + 10559488);  //     12,288
    u16*    csm      = (u16*)(ws + 10571776);    //     65,536
    float*  biasAll  = (float*)(ws + 10637312);  //     16,384
    float*  gammaAll = (float*)(ws + 10653696);  //     16,384
    float*  betaAll  = (float*)(ws + 10670080);  //     16,384
    float2* stats    = (float2*)(ws + 10686464); //  1,048,576 (max Rh*8*8)
    u16*    context  = (u16*)(ws + 11735040);    // 33,554,432
    u16*    scratch  = (u16*)(ws + 45289472);    // remainder (head_pre + partials / ctx_pre)
    u16*    W2pad    = ctxWt;
    size_t S = (ws_size > 45289472) ? ws_size - 45289472 : 0;

    int Rc = 16384;
    while ((size_t)Rc * 2048 > S && Rc > 512) Rc >>= 1;
    // head chunk needs Rh*8192 (head_pre) + Rh*128 (partials [16][Rh] float2)
    int Rh = 16384;
    while ((size_t)Rh * 8320 > S && Rh > 256) Rh >>= 1;
    float2* partials = (float2*)((char*)scratch + (size_t)Rh * 8192);

    float* out = (float*)d_out;

    SmallTab tab;
    const float* srcs[15] = { op_embed, pt_embed, pos_embed,
                              (const float*)d_in[7], (const float*)d_in[8], (const float*)d_in[9],
                              (const float*)d_in[11], (const float*)d_in[12], (const float*)d_in[13],
                              (const float*)d_in[15],
                              (const float*)d_in[18], (const float*)d_in[19], (const float*)d_in[21],
                              (const float*)d_in[23], (const float*)d_in[25] };
    const int offs[15] = { OP_E, PT_E, POS_E, CTX_B, CTX_G, CTX_BE,
                           S_B1, S_G, S_BE, S_B2,
                           D_G, D_BE, D_B2, A_B1, A_B2 };
    const int cnts[15] = { 2304, 2560, 1536, 1024, 1024, 1024,
                           512, 512, 512, 3,
                           3072, 3072, 60, 512, 1 };
    for (int i = 0; i < 15; ++i) { tab.src[i] = srcs[i]; tab.off[i] = offs[i]; tab.cnt[i] = cnts[i]; }
    convert_small<<<70, 256, 0, stream>>>(tab, csm);

    transpose_all<<<dim3(32, 32, 9), 256, 0, stream>>>(
        ctx_w, sign_w1, aux_w1, dig_w1, ctxWt, BtAll);
    precompute_bias<<<84, 256, 0, stream>>>(
        ctx_w, dig_w1, op_embed, pt_embed, pos_embed, dig_b1, op_type,
        E_op, P_pt, dbias);
    build_vec<<<16, 256, 0, stream>>>(csm, dbias, biasAll, gammaAll, betaAll);

    // hidden f32 -> bf16, overlaid on the context buffer (rows die chunk-wise
    // exactly when ln_ctx overwrites them, after this chunk's gemm consumed them)
    u16* hbf16 = context;
    convert_hidden<<<8192, 256, 0, stream>>>(hidden, hbf16, 16384 * 1024 / 8);

    // context = gelu(LN(hidden @ ctx_w[:1024] + E_op + P_pt + b))
    for (int t0 = 0; t0 < 16384; t0 += Rc) {
        gemm_8ph<false><<<dim3(Rc / 256, 4), 512, 0, stream>>>(
            hbf16 + (size_t)t0 * 1024, ctxWt, scratch, Rc, 1024, nullptr, nullptr);
        ln_ctx_kernel<<<Rc, 256, 0, stream>>>(
            scratch, E_op, P_pt, pt_type, csm, context, t0);
    }

    // W2pad overlays ctxWt (now dead)
    build_w2pad<<<2048, 256, 0, stream>>>(sign_w2, dig_w2, aux_w2, W2pad);

    // head pipeline per chunk: 8-phase GEMM (+fused LN partials) -> stats_fin
    // -> fused LN+GELU GEMM scattering straight to out (no out_pre/gather)
    for (int t0 = 0; t0 < 16384; t0 += Rh) {
        gemm_8ph<true><<<dim3(Rh / 256, 16), 512, 0, stream>>>(
            context + (size_t)t0 * 1024, BtAll, scratch, Rh, 4096,
            biasAll, partials);
        stats_fin<<<(Rh * 8 + 255) / 256, 256, 0, stream>>>(partials, stats, Rh);
        gemm_final_fused<<<Rh / 64, 512, 0, stream>>>(
            scratch, W2pad, biasAll, gammaAll, betaAll, stats, csm, out, t0);
    }
}

// Round 7
// 481.190 us; speedup vs baseline: 1.2068x; 1.0639x over previous
//
#include <hip/hip_runtime.h>
#include <hip/hip_bf16.h>

typedef unsigned short u16;
typedef __attribute__((ext_vector_type(8))) __bf16 bf16x8;
typedef __attribute__((ext_vector_type(4))) float f32x4;

typedef __attribute__((address_space(1))) const void GVoid;
typedef __attribute__((address_space(3))) void LVoid;

__device__ __forceinline__ void async_load16(const u16* g, u16* l) {
    __builtin_amdgcn_global_load_lds((GVoid*)g, (LVoid*)l, 16, 0, 0);
}

__device__ __forceinline__ float bf2f(u16 u) {
    union { unsigned i; float f; } v; v.i = ((unsigned)u) << 16; return v.f;
}
__device__ __forceinline__ u16 f2bf(float f) {
    union { float f; unsigned i; } v; v.f = f;
    unsigned r = (v.i + 0x7FFFu + ((v.i >> 16) & 1u)) >> 16;
    return (u16)r;
}
// tanh-form GELU: gelu = x*(1 - 1/(1+e^{2t})), t=0.79788x+0.035677x^3
__device__ __forceinline__ float gelu_f(float x) {
    float t = x * fmaf(0.0356774081f, x * x, 0.7978845608f);
    float e = __expf(2.0f * t);
    float r = 1.0f / (e + 1.0f);
    return x - x * r;
}

// element offsets inside the canonical small-vector buffer (u16, bf16 values)
#define OP_E   0
#define PT_E   2304
#define POS_E  4864
#define CTX_B  6400
#define CTX_G  7424
#define CTX_BE 8448
#define S_B1   9472
#define S_G    9984
#define S_BE   10496
#define S_B2   11008
#define D_G    11012
#define D_BE   14084
#define D_B2   17156
#define A_B1   17216
#define A_B2   17728

// ---------------------------------------------------------------------------
struct SmallTab {
    const float* src[15];
    int off[15];
    int cnt[15];
};

__global__ __launch_bounds__(256) void convert_small(SmallTab tab, u16* __restrict__ dst)
{
    int idx = blockIdx.x * 256 + threadIdx.x;
#pragma unroll
    for (int e = 0; e < 15; ++e) {
        if (idx < tab.cnt[e]) {
            dst[tab.off[e] + idx] = f2bf(tab.src[e][idx]);
            return;
        }
        idx -= tab.cnt[e];
    }
}

// ---------------------------------------------------------------------------
// hidden f32 -> bf16, 16B/thread streaming.
// ---------------------------------------------------------------------------
__global__ __launch_bounds__(256) void convert_hidden(
    const float* __restrict__ src, u16* __restrict__ dst, int n8)
{
    int i = blockIdx.x * 256 + threadIdx.x;
    if (i >= n8) return;
    const float4* p = (const float4*)(src + (size_t)i * 8);
    float4 a = p[0], b = p[1];
    uint4 o;
    o.x = f2bf(a.x) | ((unsigned)f2bf(a.y) << 16);
    o.y = f2bf(a.z) | ((unsigned)f2bf(a.w) << 16);
    o.z = f2bf(b.x) | ((unsigned)f2bf(b.y) << 16);
    o.w = f2bf(b.z) | ((unsigned)f2bf(b.w) << 16);
    *(uint4*)(dst + (size_t)i * 8) = o;
}

// ---------------------------------------------------------------------------
// Transpose fp32 weights to B^T ([N,K] row-major) bf16.
// ---------------------------------------------------------------------------
__global__ __launch_bounds__(256) void transpose_all(
    const float* __restrict__ ctx_w, const float* __restrict__ sign_w1,
    const float* __restrict__ aux_w1, const float* __restrict__ dig_w1,
    u16* __restrict__ ctxWt, u16* __restrict__ BtAll)
{
    __shared__ u16 tl[32][33];
    int z = blockIdx.z;
    const float* src; u16* dst; size_t srcOff = 0; int srcLd, cols;
    if (z == 8) { src = ctx_w; dst = ctxWt; srcLd = 1024; cols = 1024; }
    else {
        srcLd = 512; cols = 512;
        if (z == 0) src = sign_w1;
        else if (z == 1) src = aux_w1;
        else { src = dig_w1; srcOff = (size_t)(z - 2) * 1280 * 512; }
        dst = BtAll + (size_t)z * 512 * 1024;
    }
    int n0 = blockIdx.x * 32;
    if (n0 >= cols) return;
    int k0 = blockIdx.y * 32;
    int t = threadIdx.x;
    int r = t >> 3;
    int c4 = (t & 7) * 4;
    float4 v = *(const float4*)&src[srcOff + (size_t)(k0 + r) * srcLd + n0 + c4];
    tl[r][c4 + 0] = f2bf(v.x); tl[r][c4 + 1] = f2bf(v.y);
    tl[r][c4 + 2] = f2bf(v.z); tl[r][c4 + 3] = f2bf(v.w);
    __syncthreads();
    ushort4 o;
    o.x = tl[c4 + 0][r]; o.y = tl[c4 + 1][r]; o.z = tl[c4 + 2][r]; o.w = tl[c4 + 3][r];
    *(ushort4*)&dst[(size_t)(n0 + r) * 1024 + k0 + c4] = o;
}

// ---------------------------------------------------------------------------
// Row-bias precompute (fp32 out)
// ---------------------------------------------------------------------------
__global__ __launch_bounds__(256) void precompute_bias(
    const float* __restrict__ ctx_w, const float* __restrict__ dig_w1,
    const float* __restrict__ op_embed, const float* __restrict__ pt_embed,
    const float* __restrict__ pos_embed, const float* __restrict__ dig_b1,
    const int* __restrict__ op_type,
    float* __restrict__ E_op, float* __restrict__ P_pt, float* __restrict__ dbias)
{
    int idx = blockIdx.x * 256 + threadIdx.x;
    if (idx < 8192) {
        int b = idx >> 10, n = idx & 1023;
        const float* e = op_embed + op_type[b] * 256;
        float s = 0.f;
        for (int q = 0; q < 256; ++q)
            s += e[q] * ctx_w[(size_t)(1024 + q) * 1024 + n];
        E_op[idx] = s;
    } else if (idx < 18432) {
        int i = idx - 8192;
        int v = i >> 10, n = i & 1023;
        const float* e = pt_embed + v * 256;
        float s = 0.f;
        for (int q = 0; q < 256; ++q)
            s += e[q] * ctx_w[(size_t)(1280 + q) * 1024 + n];
        P_pt[i] = s;
    } else if (idx < 21504) {
        int i = idx - 18432;
        int p = i >> 9, h = i & 511;
        const float* e = pos_embed + p * 256;
        float s = dig_b1[p * 512 + h];
        for (int q = 0; q < 256; ++q)
            s += e[q] * dig_w1[(size_t)p * 1280 * 512 + (size_t)(1024 + q) * 512 + h];
        dbias[i] = s;
    }
}

// ---------------------------------------------------------------------------
// Unified per-column vectors over the 4096 head_pre columns (fp32).
// ---------------------------------------------------------------------------
__global__ __launch_bounds__(256) void build_vec(
    const u16* __restrict__ csm, const float* __restrict__ dbias,
    float* __restrict__ biasAll, float* __restrict__ gammaAll,
    float* __restrict__ betaAll)
{
    int n = blockIdx.x * 256 + threadIdx.x;   // 0..4095
    float bi, g, be;
    if (n < 512) {
        bi = bf2f(csm[S_B1 + n]); g = bf2f(csm[S_G + n]); be = bf2f(csm[S_BE + n]);
    } else if (n < 1024) {
        bi = bf2f(csm[A_B1 + n - 512]); g = 1.f; be = 0.f;
    } else {
        int h = n - 1024;
        bi = dbias[h]; g = bf2f(csm[D_G + h]); be = bf2f(csm[D_BE + h]);
    }
    biasAll[n] = bi; gammaAll[n] = g; betaAll[n] = be;
}

// ---------------------------------------------------------------------------
// Build block-diagonal W2pad [128, 4096] bf16. Row = r*16+o.
// ---------------------------------------------------------------------------
__global__ __launch_bounds__(256) void build_w2pad(
    const float* __restrict__ sign_w2, const float* __restrict__ dig_w2,
    const float* __restrict__ aux_w2, u16* __restrict__ W2pad)
{
    int idx = blockIdx.x * 256 + threadIdx.x;   // 128*4096
    int row = idx >> 12, k = idx & 4095;
    int r = row >> 4, o = row & 15;
    float v = 0.f;
    if (r == 0) {
        if (o < 3 && k < 512) v = sign_w2[k * 3 + o];
    } else if (r == 7) {
        if (o == 0 && k >= 512 && k < 1024) v = aux_w2[k - 512];
    } else {
        int p = r - 1, lo = 1024 + p * 512;
        if (o < 10 && k >= lo && k < lo + 512) v = dig_w2[(size_t)p * 5120 + (k - lo) * 10 + o];
    }
    W2pad[idx] = f2bf(v);
}

// ---------------------------------------------------------------------------
// stats_fin: combine the two 256-col partials per (row, 512-slice) ->
// (mean, rstd); aux slice (s==1) identity. partials layout: [16][Rh] float2.
// ---------------------------------------------------------------------------
__global__ __launch_bounds__(256) void stats_fin(
    const float2* __restrict__ partials, float2* __restrict__ stats, int Rh)
{
    int i = blockIdx.x * 256 + threadIdx.x;
    if (i >= Rh * 8) return;
    int row = i >> 3, s = i & 7;
    float2 o;
    if (s == 1) {
        o = make_float2(0.f, 1.f);
    } else {
        float2 a = partials[(size_t)(2 * s) * Rh + row];
        float2 b = partials[(size_t)(2 * s + 1) * Rh + row];
        float sm = a.x + b.x, s2 = a.y + b.y;
        float mean = sm * (1.f / 512.f);
        float var = fmaxf(s2 * (1.f / 512.f) - mean * mean, 0.f);
        o = make_float2(mean, rsqrtf(var + 1e-5f));
    }
    stats[i] = o;
}

// ---------------------------------------------------------------------------
// GEMM, 256x256-tile 8-phase schedule (m201 structure, plain HIP).
// C[M,N] = A[M,1024] @ Bt[N,1024]^T, bf16 in/out. M,N % 256 == 0, K = 1024.
//
// XCD mapping (round-7): 2D partition PM x PN (PM*PN=8). XCD x = flat&7 owns
// an (Mtiles/PM) x (Ntiles/PN) rectangle; local index l = flat>>3 walks
// bn-fast, so the XCD's B-chunk (<=2 MB) goes L2-resident and each A row is
// fetched ONCE per XCD (round-6 lesson: the 1-D column swizzle streamed the
// ENTIRE A through every XCD's L2 -> FETCH = 8 x A = 270 MB).
// Requires Mtiles%PM==0 && Ntiles%PN==0 (host guarantees).
//
// 8 waves (2Mx4N), 512 thr, BK=64, LDS 128 KiB = 2 dbuf x {A,B} x 2 half x
// [128 rows][8 granules of 16B], granule slot XOR-swizzled with (row&7) (T2).
// global_load_lds dest is linear; the global SOURCE is inverse-swizzled (the
// same involution), so swizzle is both-sides (rule #21).
// Per K-tile: 4 phases x {stage 1 half-tile, 16 MFMA}, one counted
// s_waitcnt vmcnt(6) per tile (T3/T4), setprio around MFMA clusters (T5).
//
// STATS=true (head GEMM): f2bf computed ONCE per element (cv), shared by
// stats and C-write (round-5 lesson). Stats via LDS transpose-reduce in the
// dead smem (rounds 3/4 lessons: no device-scope atomics, no deep shfl).
// ---------------------------------------------------------------------------
template<bool STATS>
__global__ __launch_bounds__(512) void gemm_8ph(
    const u16* __restrict__ A, const u16* __restrict__ Bt, u16* __restrict__ C,
    int M, int N, int PM, int PN,
    const float* __restrict__ biasAll, float2* __restrict__ partials)
{
    __shared__ u16 smem[65536];   // 128 KiB
    const int tid = threadIdx.x;
    const int wid = tid >> 6, lane = tid & 63;
    const int quad = lane >> 4, r16 = lane & 15;
    const int wm = wid >> 2, wn = wid & 3;

    // 2D XCD partition, bn-fast local order
    const int Mtiles = M >> 8, Ntiles = N >> 8;
    int flat = blockIdx.x + blockIdx.y * gridDim.x;
    int x = flat & 7, l = flat >> 3;
    int Mloc = Mtiles / PM, Nloc = Ntiles / PN;
    int xm = x / PN, xn = x - xm * PN;
    int bm = xm * Mloc + l / Nloc;
    int bn = xn * Nloc + l % Nloc;
    const int m0 = bm << 8, n0 = bn << 8;

    // staging geometry: granule g = l*512 + tid; row = g>>3, slot = g&7
    // logical col granule = slot ^ (row&7)  (involution)
    const int rb = tid >> 3;                       // row within 64-row chunk
    const int cx = ((tid & 7) ^ (rb & 7)) * 8;     // inverse-swizzled col (elems)
    const u16* gA = A + (size_t)(m0 + rb) * 1024 + cx;
    const u16* gB = Bt + (size_t)(n0 + rb) * 1024 + cx;

#define STAGE(arr, h, tt) do { \
        u16* _d = smem + ((((tt) & 1) * 2 + (arr)) * 2 + (h)) * 8192 + wid * 512; \
        const u16* _s = ((arr) ? gB : gA) + (size_t)((h) * 128) * 1024 + (tt) * 64; \
        async_load16(_s, _d); \
        async_load16(_s + (size_t)64 * 1024, _d + 4096); \
    } while (0)

    // prologue: tile 0 fully (4 halves), tile 1 first 3 halves -> 14 loads;
    // vmcnt(6) completes exactly tile 0, leaves 3 half-tiles in flight.
    STAGE(0, 0, 0); STAGE(0, 1, 0); STAGE(1, 0, 0); STAGE(1, 1, 0);
    STAGE(0, 0, 1); STAGE(0, 1, 1); STAGE(1, 0, 1);
    asm volatile("s_waitcnt vmcnt(6)" ::: "memory");
    asm volatile("s_barrier" ::: "memory");

    f32x4 acc[8][4] = {};
    const int kx0 = ((quad) ^ (r16 & 7)) * 8;       // ks=0 swizzled slot (elems)
    const int kx1 = ((4 + quad) ^ (r16 & 7)) * 8;   // ks=1

#define QUAD(MF0, NF0) \
        _Pragma("unroll") \
        for (int ks = 0; ks < 2; ++ks) \
            _Pragma("unroll") \
            for (int mi = 0; mi < 4; ++mi) \
                _Pragma("unroll") \
                for (int nj = 0; nj < 2; ++nj) \
                    acc[(MF0) + mi][(NF0) + nj] = \
                        __builtin_amdgcn_mfma_f32_16x16x32_bf16( \
                            afr[(MF0) + mi][ks], bfr[(NF0) + nj][ks], \
                            acc[(MF0) + mi][(NF0) + nj], 0, 0, 0);

    for (int t = 0; t < 16; ++t) {
        const int cur = t & 1;
        const u16* sA = smem + cur * 32768 + wm * 8192 + r16 * 64;
        const u16* sB = smem + cur * 32768 + 16384 + (wn >> 1) * 8192
                        + ((wn & 1) * 64 + r16) * 64;

        // ---- phase 0: stage B-hi(t+1) [nxt buf]; read ALL frags; quad (0,0)
        if (t + 1 < 16) STAGE(1, 1, t + 1);
        bf16x8 afr[8][2], bfr[4][2];
#pragma unroll
        for (int mf = 0; mf < 8; ++mf) {
            afr[mf][0] = *(const bf16x8*)&sA[mf * 1024 + kx0];
            afr[mf][1] = *(const bf16x8*)&sA[mf * 1024 + kx1];
        }
#pragma unroll
        for (int nf = 0; nf < 4; ++nf) {
            bfr[nf][0] = *(const bf16x8*)&sB[nf * 1024 + kx0];
            bfr[nf][1] = *(const bf16x8*)&sB[nf * 1024 + kx1];
        }
        __builtin_amdgcn_s_setprio(1);
        QUAD(0, 0)
        __builtin_amdgcn_s_setprio(0);
        // fence: ALL reads of buf[cur] complete before any wave may issue a
        // stage that overwrites it (phases 1-3)
        asm volatile("s_waitcnt lgkmcnt(0)" ::: "memory");
        __builtin_amdgcn_sched_barrier(0);
        asm volatile("s_barrier" ::: "memory");
        __builtin_amdgcn_sched_barrier(0);

        // ---- phase 1: stage A-lo(t+2) [cur buf, now dead]; quad (0,1)
        if (t + 2 < 16) STAGE(0, 0, t + 2);
        __builtin_amdgcn_sched_barrier(0);
        __builtin_amdgcn_s_setprio(1);
        QUAD(0, 2)
        __builtin_amdgcn_s_setprio(0);
        __builtin_amdgcn_sched_barrier(0);
        asm volatile("s_barrier" ::: "memory");
        __builtin_amdgcn_sched_barrier(0);

        // ---- phase 2: stage A-hi(t+2); quad (1,0)
        if (t + 2 < 16) STAGE(0, 1, t + 2);
        __builtin_amdgcn_sched_barrier(0);
        __builtin_amdgcn_s_setprio(1);
        QUAD(4, 0)
        __builtin_amdgcn_s_setprio(0);
        __builtin_amdgcn_sched_barrier(0);
        asm volatile("s_barrier" ::: "memory");
        __builtin_amdgcn_sched_barrier(0);

        // ---- phase 3: stage B-lo(t+2); quad (1,1); counted vmcnt
        if (t + 2 < 16) STAGE(1, 0, t + 2);
        __builtin_amdgcn_sched_barrier(0);
        __builtin_amdgcn_s_setprio(1);
        QUAD(4, 2)
        __builtin_amdgcn_s_setprio(0);
        __builtin_amdgcn_sched_barrier(0);
        // steady state: 14 outstanding; oldest 8 = tile t+1's four halves
        if (t < 14)       asm volatile("s_waitcnt vmcnt(6)" ::: "memory");
        else if (t == 14) asm volatile("s_waitcnt vmcnt(0)" ::: "memory");
        asm volatile("s_barrier" ::: "memory");
    }
#undef QUAD
#undef STAGE

    // epilogue: per-mf group, convert once (cv), optional stats, C-write.
    float bnf[4];
    float2* lds2 = (float2*)smem;   // [256 rows][64 slots] float2 (dead smem)
    int sstat = 0, prp = 0, parp = 0;
    if constexpr (STATS) {
#pragma unroll
        for (int nf = 0; nf < 4; ++nf)
            bnf[nf] = biasAll[n0 + wn * 64 + nf * 16 + r16];
        sstat = wn * 16 + r16; prp = sstat >> 1; parp = sstat & 1;
    }
#pragma unroll
    for (int mf = 0; mf < 8; ++mf) {
        u16 cvm[4][4];
#pragma unroll
        for (int nf = 0; nf < 4; ++nf)
#pragma unroll
            for (int r = 0; r < 4; ++r)
                cvm[nf][r] = f2bf(acc[mf][nf][r]);
        if constexpr (STATS) {
#pragma unroll
            for (int r = 0; r < 4; ++r) {
                float sv = 0.f, s2v = 0.f;
#pragma unroll
                for (int nf = 0; nf < 4; ++nf) {
                    float v = bf2f(cvm[nf][r]) + bnf[nf];
                    sv += v; s2v += v * v;
                }
                int lr = wm * 128 + mf * 16 + quad * 4 + r;
                int pp = ((prp + lr) & 31) * 2 + parp;     // rotated slot
                lds2[lr * 64 + pp] = make_float2(sv, s2v);
            }
        }
#pragma unroll
        for (int nf = 0; nf < 4; ++nf) {
            size_t base = (size_t)(m0 + wm * 128 + mf * 16 + quad * 4) * N
                          + n0 + wn * 64 + nf * 16 + r16;
#pragma unroll
            for (int r = 0; r < 4; ++r)
                C[base + (size_t)r * N] = cvm[nf][r];
        }
    }
    if constexpr (STATS) {
        __syncthreads();
        // combine: 512 threads, each sums half a row (32 float2 = 16 b128 reads)
        int row = tid >> 1, half = tid & 1;
        float sv = 0.f, s2v = 0.f;
#pragma unroll
        for (int i = 0; i < 16; ++i) {
            int pp = ((half * 16 + i + row) & 31) * 2;   // same rotation
            f32x4 q = *(const f32x4*)&lds2[row * 64 + pp];
            sv += q[0] + q[2]; s2v += q[1] + q[3];
        }
        sv += __shfl_xor(sv, 1); s2v += __shfl_xor(s2v, 1);
        if (half == 0)
            partials[(size_t)bn * M + m0 + row] = make_float2(sv, s2v);
    }
}

// ---------------------------------------------------------------------------
// ctx LN+GELU
// ---------------------------------------------------------------------------
__global__ __launch_bounds__(256) void ln_ctx_kernel(
    const u16* __restrict__ pre, const float* __restrict__ E_op,
    const float* __restrict__ P_pt, const int* __restrict__ ptype,
    const u16* __restrict__ csm, u16* __restrict__ ctx, int tokOff)
{
    __shared__ float red[8];
    int local = blockIdx.x;
    int token = tokOff + local;
    int b = token >> 11;            // T = 2048
    int pt = ptype[token];
    int tid = threadIdx.x;
    int c = tid * 4;
    int wid = tid >> 6, lane = tid & 63;

    ushort4 xp = *(const ushort4*)&pre[(size_t)local * 1024 + c];
    float4 eo = *(const float4*)&E_op[b * 1024 + c];
    float4 pp = *(const float4*)&P_pt[pt * 1024 + c];
    ushort4 cb4 = *(const ushort4*)&csm[CTX_B + c];
    float x[4];
    x[0] = bf2f(xp.x) + eo.x + pp.x + bf2f(cb4.x);
    x[1] = bf2f(xp.y) + eo.y + pp.y + bf2f(cb4.y);
    x[2] = bf2f(xp.z) + eo.z + pp.z + bf2f(cb4.z);
    x[3] = bf2f(xp.w) + eo.w + pp.w + bf2f(cb4.w);

    float s = x[0] + x[1] + x[2] + x[3];
    float s2 = x[0]*x[0] + x[1]*x[1] + x[2]*x[2] + x[3]*x[3];
    for (int off = 32; off; off >>= 1) { s += __shfl_xor(s, off); s2 += __shfl_xor(s2, off); }
    if (lane == 0) { red[wid] = s; red[4 + wid] = s2; }
    __syncthreads();
    s  = red[0] + red[1] + red[2] + red[3];
    s2 = red[4] + red[5] + red[6] + red[7];
    float mean = s * (1.f / 1024.f);
    float var = fmaxf(s2 * (1.f / 1024.f) - mean * mean, 0.f);
    float rs = rsqrtf(var + 1e-5f);

    ushort4 g4 = *(const ushort4*)&csm[CTX_G + c];
    ushort4 b4 = *(const ushort4*)&csm[CTX_BE + c];
    ushort4 o;
    o.x = f2bf(gelu_f((x[0] - mean) * rs * bf2f(g4.x) + bf2f(b4.x)));
    o.y = f2bf(gelu_f((x[1] - mean) * rs * bf2f(g4.y) + bf2f(b4.y)));
    o.z = f2bf(gelu_f((x[2] - mean) * rs * bf2f(g4.z) + bf2f(b4.z)));
    o.w = f2bf(gelu_f((x[3] - mean) * rs * bf2f(g4.w) + bf2f(b4.w)));
    *(ushort4*)&ctx[(size_t)token * 1024 + c] = o;
}

// ---------------------------------------------------------------------------
// gemm_final_fused: out = (gelu(LN(A)) @ W2pad^T + out-bias) scattered
// directly into the three output regions. Full K=4096 per block.
//
// Round-7: M-tile 32, 256 threads (4 waves, each owning 2 output col-groups)
// — the 64-row version ran 128 blocks on 256 CUs (half the GPU idle at
// Rh=8192). 20 KiB LDS -> multi-block occupancy. Same both-sides XOR swizzle
// (all row bases = 0 mod 8 so the involution is unchanged); stats st uniform
// per sl (static indexing, rule #20); one-step A-reg prefetch.
// ---------------------------------------------------------------------------
__global__ __launch_bounds__(256) void gemm_final_fused(
    const u16* __restrict__ A, const u16* __restrict__ W2pad,
    const float* __restrict__ biasAll, const float* __restrict__ gammaAll,
    const float* __restrict__ betaAll, const float2* __restrict__ stats,
    const u16* __restrict__ csm, float* __restrict__ out, int tokOff)
{
    __shared__ u16 As[32 * 64];     //  4 KiB
    __shared__ u16 Bs[128 * 64];    // 16 KiB
    const int tid = threadIdx.x;
    const int wid = tid >> 6, lane = tid & 63;
    const int quad = lane >> 4, r16 = lane & 15;
    const int m0 = blockIdx.x * 32;

    // A staging: row r0 (0..31), logical granule lg, swizzled phys granule
    const int r0 = tid >> 3;
    const int lg = tid & 7;
    const int c8 = lg * 8;
    const int pgA = ((lg ^ (r0 & 7)) * 8);
    const u16* arow = A + (size_t)(m0 + r0) * 4096;

    // B staging: 4 calls; call h covers rows h*32 + r0; source granule
    // inverse-swizzled so linear LDS dest yields swizzled logical layout.
    const int bcol = ((tid & 7) ^ (r0 & 7)) * 8;
    const u16* brow = W2pad + (size_t)r0 * 4096 + bcol;

    f32x4 acc[2][2] = {};

    uint4 xa = *(const uint4*)(arow + c8);      // prefetch k0 = 0

    for (int sl = 0; sl < 8; ++sl) {
        const float2 st = stats[(m0 + r0) * 8 + sl];
        for (int kb = 0; kb < 8; ++kb) {
            const int k0 = sl * 512 + kb * 64;
            // stage B[128][64] (4 x 4KB calls, linear dest)
#pragma unroll
            for (int h = 0; h < 4; ++h)
                async_load16(brow + (size_t)(h * 32) * 4096 + k0,
                             Bs + h * 2048 + tid * 8);
            // prefetch next A chunk
            uint4 xn = xa;
            if (k0 + 64 < 4096) xn = *(const uint4*)(arow + k0 + 64 + c8);
            // LN+GELU on current 8 elems
            const int kk = k0 + c8;
            float4 bi0 = *(const float4*)&biasAll[kk],  bi1 = *(const float4*)&biasAll[kk + 4];
            float4 g0  = *(const float4*)&gammaAll[kk], g1  = *(const float4*)&gammaAll[kk + 4];
            float4 be0 = *(const float4*)&betaAll[kk],  be1 = *(const float4*)&betaAll[kk + 4];
            float bb[8] = {bi0.x, bi0.y, bi0.z, bi0.w, bi1.x, bi1.y, bi1.z, bi1.w};
            float gg[8] = {g0.x, g0.y, g0.z, g0.w, g1.x, g1.y, g1.z, g1.w};
            float bt[8] = {be0.x, be0.y, be0.z, be0.w, be1.x, be1.y, be1.z, be1.w};
            u16 xr[8]; *(uint4*)&xr[0] = xa;
            u16 o[8];
#pragma unroll
            for (int j = 0; j < 8; ++j) {
                float v = (bf2f(xr[j]) + bb[j] - st.x) * st.y * gg[j] + bt[j];
                o[j] = f2bf(gelu_f(v));
            }
            *(uint4*)&As[r0 * 64 + pgA] = *(const uint4*)&o[0];
            __syncthreads();

            bf16x8 af[2][2], bw[2][2];
#pragma unroll
            for (int ks = 0; ks < 2; ++ks) {
                int pg = ((ks * 4 + quad) ^ (r16 & 7)) * 8;
#pragma unroll
                for (int i = 0; i < 2; ++i)
                    af[i][ks] = *(const bf16x8*)&As[(i * 16 + r16) * 64 + pg];
#pragma unroll
                for (int j = 0; j < 2; ++j)
                    bw[j][ks] = *(const bf16x8*)&Bs[((wid * 2 + j) * 16 + r16) * 64 + pg];
            }
#pragma unroll
            for (int ks = 0; ks < 2; ++ks)
#pragma unroll
                for (int i = 0; i < 2; ++i)
#pragma unroll
                    for (int j = 0; j < 2; ++j)
                        acc[i][j] = __builtin_amdgcn_mfma_f32_16x16x32_bf16(
                            af[i][ks], bw[j][ks], acc[i][j], 0, 0, 0);
            __syncthreads();
            xa = xn;
        }
    }

    // scatter epilogue: wave wid owns output col-groups {2*wid, 2*wid+1}
#pragma unroll
    for (int j = 0; j < 2; ++j) {
        const int cg = wid * 2 + j, o = r16;
        int mode = -1; float obias = 0.f;
        if (cg == 0)      { if (o < 3)  { mode = 0; obias = bf2f(csm[S_B2 + o]); } }
        else if (cg == 7) { if (o == 0) { mode = 2; obias = bf2f(csm[A_B2]); } }
        else              { if (o < 10) { mode = 1; obias = bf2f(csm[D_B2 + (cg - 1) * 10 + o]); } }
        if (mode >= 0) {
#pragma unroll
            for (int i = 0; i < 2; ++i)
#pragma unroll
                for (int r = 0; r < 4; ++r) {
                    int token = tokOff + m0 + i * 16 + quad * 4 + r;
                    float v = acc[i][j][r] + obias;
                    if (mode == 0)      out[(size_t)token * 3 + o] = v;
                    else if (mode == 1) out[49152 + ((size_t)token * 6 + (cg - 1)) * 10 + o] = v;
                    else                out[1032192 + (size_t)token] = v;
                }
        }
    }
}

// ---------------------------------------------------------------------------
extern "C" void kernel_launch(void* const* d_in, const int* in_sizes, int n_in,
                              void* d_out, int out_size, void* d_ws, size_t ws_size,
                              hipStream_t stream) {
    const float* hidden    = (const float*)d_in[0];
    const int*   op_type   = (const int*)d_in[1];
    const int*   pt_type   = (const int*)d_in[2];
    const float* op_embed  = (const float*)d_in[3];
    const float* pt_embed  = (const float*)d_in[4];
    const float* pos_embed = (const float*)d_in[5];
    const float* ctx_w     = (const float*)d_in[6];
    const float* sign_w1   = (const float*)d_in[10];
    const float* sign_w2   = (const float*)d_in[14];
    const float* dig_w1    = (const float*)d_in[16];
    const float* dig_b1    = (const float*)d_in[17];
    const float* dig_w2    = (const float*)d_in[20];
    const float* aux_w1    = (const float*)d_in[22];
    const float* aux_w2    = (const float*)d_in[24];

    char* ws = (char*)d_ws;
    u16*    ctxWt    = (u16*)(ws + 0);           //  2,097,152 (later W2pad overlay)
    u16*    BtAll    = (u16*)(ws + 2097152);     //  8,388,608
    float*  E_op     = (float*)(ws + 10485760);  //     32,768
    float*  P_pt     = (float*)(ws + 10518528);  //     40,960
    float*  dbias    = (float*)(ws + 10559488);  //     12,288
    u16*    csm      = (u16*)(ws + 10571776);    //     65,536
    float*  biasAll  = (float*)(ws + 10637312);  //     16,384
    float*  gammaAll = (float*)(ws + 10653696);  //     16,384
    float*  betaAll  = (float*)(ws + 10670080);  //     16,384
    float2* stats    = (float2*)(ws + 10686464); //  1,048,576 (max Rh*8*8)
    u16*    context  = (u16*)(ws + 11735040);    // 33,554,432
    u16*    scratch  = (u16*)(ws + 45289472);    // remainder (head_pre + partials / ctx_pre)
    u16*    W2pad    = ctxWt;
    size_t S = (ws_size > 45289472) ? ws_size - 45289472 : 0;

    int Rc = 16384;
    while ((size_t)Rc * 2048 > S && Rc > 512) Rc >>= 1;
    // head chunk needs Rh*8192 (head_pre) + Rh*128 (partials [16][Rh] float2)
    int Rh = 16384;
    while ((size_t)Rh * 8320 > S && Rh > 256) Rh >>= 1;
    float2* partials = (float2*)((char*)scratch + (size_t)Rh * 8192);

    // XCD partition shapes (Mtiles%PM==0 and Ntiles%PN==0 required)
    int PMh = 2, PNh = 4;
    if (((Rh >> 8) & 1) != 0) { PMh = 1; PNh = 8; }     // Rh==256 edge
    int PMc = 8, PNc = 1;
    if (((Rc >> 8) % 8) != 0) { PMc = 2; PNc = 4; }     // small-Rc edge

    float* out = (float*)d_out;

    SmallTab tab;
    const float* srcs[15] = { op_embed, pt_embed, pos_embed,
                              (const float*)d_in[7], (const float*)d_in[8], (const float*)d_in[9],
                              (const float*)d_in[11], (const float*)d_in[12], (const float*)d_in[13],
                              (const float*)d_in[15],
                              (const float*)d_in[18], (const float*)d_in[19], (const float*)d_in[21],
                              (const float*)d_in[23], (const float*)d_in[25] };
    const int offs[15] = { OP_E, PT_E, POS_E, CTX_B, CTX_G, CTX_BE,
                           S_B1, S_G, S_BE, S_B2,
                           D_G, D_BE, D_B2, A_B1, A_B2 };
    const int cnts[15] = { 2304, 2560, 1536, 1024, 1024, 1024,
                           512, 512, 512, 3,
                           3072, 3072, 60, 512, 1 };
    for (int i = 0; i < 15; ++i) { tab.src[i] = srcs[i]; tab.off[i] = offs[i]; tab.cnt[i] = cnts[i]; }
    convert_small<<<70, 256, 0, stream>>>(tab, csm);

    transpose_all<<<dim3(32, 32, 9), 256, 0, stream>>>(
        ctx_w, sign_w1, aux_w1, dig_w1, ctxWt, BtAll);
    precompute_bias<<<84, 256, 0, stream>>>(
        ctx_w, dig_w1, op_embed, pt_embed, pos_embed, dig_b1, op_type,
        E_op, P_pt, dbias);
    build_vec<<<16, 256, 0, stream>>>(csm, dbias, biasAll, gammaAll, betaAll);

    // hidden f32 -> bf16, overlaid on the context buffer (rows die chunk-wise
    // exactly when ln_ctx overwrites them, after this chunk's gemm consumed them)
    u16* hbf16 = context;
    convert_hidden<<<8192, 256, 0, stream>>>(hidden, hbf16, 16384 * 1024 / 8);

    // context = gelu(LN(hidden @ ctx_w[:1024] + E_op + P_pt + b))
    for (int t0 = 0; t0 < 16384; t0 += Rc) {
        gemm_8ph<false><<<dim3(Rc / 256, 4), 512, 0, stream>>>(
            hbf16 + (size_t)t0 * 1024, ctxWt, scratch, Rc, 1024, PMc, PNc,
            nullptr, nullptr);
        ln_ctx_kernel<<<Rc, 256, 0, stream>>>(
            scratch, E_op, P_pt, pt_type, csm, context, t0);
    }

    // W2pad overlays ctxWt (now dead)
    build_w2pad<<<2048, 256, 0, stream>>>(sign_w2, dig_w2, aux_w2, W2pad);

    // head pipeline per chunk: 8-phase GEMM (+fused LN partials) -> stats_fin
    // -> fused LN+GELU GEMM scattering straight to out (no out_pre/gather)
    for (int t0 = 0; t0 < 16384; t0 += Rh) {
        gemm_8ph<true><<<dim3(Rh / 256, 16), 512, 0, stream>>>(
            context + (size_t)t0 * 1024, BtAll, scratch, Rh, 4096, PMh, PNh,
            biasAll, partials);
        stats_fin<<<(Rh * 8 + 255) / 256, 256, 0, stream>>>(partials, stats, Rh);
        gemm_final_fused<<<Rh / 32, 256, 0, stream>>>(
            scratch, W2pad, biasAll, gammaAll, betaAll, stats, csm, out, t0);
    }
}